// Round 1
// baseline (1793.818 us; speedup 1.0000x reference)
//
#include <hip/hip_runtime.h>

#define N_NODES 50000
#define N_EDGES 400000
#define R_DIM   32
#define F_DIM   132
#define EV_DIM  15
#define H_INV_N 4
#define D_INV_N 33
#define H_EV_N  3
#define D_EV_N  44
#define F_Q     33      // F/4
#define INT_DIM 135
#define TE      16      // edges per block in edge kernel

#define RCP_NORM_INV 0.17407765595569785f  // 1/sqrt(33)
#define RCP_NORM_EV  0.15075567228888181f  // 1/sqrt(44)

__device__ __forceinline__ float silu_f(float x) {
    return x / (1.f + __expf(-x));
}

// ---------------------------------------------------------------------------
// Kernel 1: per-node projections q/k/v_inv (4 heads x 33), q/k_ev (3 heads x 44)
// block = 256 threads = 4 nodes x 64 lanes
// ---------------------------------------------------------------------------
__global__ __launch_bounds__(256) void node_proj_kernel(
    const float* __restrict__ x,
    const float* __restrict__ Wq_inv, const float* __restrict__ Wk_inv,
    const float* __restrict__ Wv_inv,
    const float* __restrict__ Wq_ev, const float* __restrict__ Wk_ev,
    float* __restrict__ q_inv, float* __restrict__ k_inv, float* __restrict__ v_inv,
    float* __restrict__ q_ev, float* __restrict__ k_ev)
{
    __shared__ float xs[4][F_DIM];
    int node0 = blockIdx.x * 4;
    for (int i = threadIdx.x; i < 4 * F_DIM; i += 256) {
        int nb = i / F_DIM, j = i - nb * F_DIM;
        xs[nb][j] = x[(size_t)(node0 + nb) * F_DIM + j];
    }
    __syncthreads();
    int nb = threadIdx.x >> 6;
    int lane = threadIdx.x & 63;
    int n = node0 + nb;
    const float* xr = xs[nb];
    for (int o = lane; o < 5 * F_DIM; o += 64) {
        int arr = o / F_DIM, ch = o - arr * F_DIM;
        float acc = 0.f;
        if (arr < 3) {
            int h = ch / D_INV_N, e = ch - h * D_INV_N;
            const float* W = (arr == 0 ? Wq_inv : (arr == 1 ? Wk_inv : Wv_inv))
                             + h * D_INV_N * D_INV_N + e;
            const float* xh = xr + h * D_INV_N;
            #pragma unroll
            for (int d = 0; d < D_INV_N; ++d) acc += xh[d] * W[d * D_INV_N];
            if (arr < 2) acc = silu_f(acc);
            float* dst = (arr == 0 ? q_inv : (arr == 1 ? k_inv : v_inv));
            dst[(size_t)n * F_DIM + ch] = acc;
        } else {
            int h = ch / D_EV_N, e = ch - h * D_EV_N;
            const float* W = (arr == 3 ? Wq_ev : Wk_ev) + h * D_EV_N * D_EV_N + e;
            const float* xh = xr + h * D_EV_N;
            #pragma unroll
            for (int d = 0; d < D_EV_N; ++d) acc += xh[d] * W[d * D_EV_N];
            acc = silu_f(acc);
            float* dst = (arr == 3 ? q_ev : k_ev);
            dst[(size_t)n * F_DIM + ch] = acc;
        }
    }
}

// ---------------------------------------------------------------------------
// Kernel 2: per-edge filters + attention + scatter (atomics)
// block = 256 threads, TE=16 edges/block
// ---------------------------------------------------------------------------
__global__ __launch_bounds__(256) void edge_kernel(
    const float* __restrict__ ev_feat,
    const float* __restrict__ rbf,
    const float* __restrict__ sh_vec,
    const float* __restrict__ cutoffs,
    const int* __restrict__ senders,
    const int* __restrict__ receivers,
    const float* __restrict__ fi_rW1, const float* __restrict__ fi_rb1,
    const float* __restrict__ fi_rW2, const float* __restrict__ fi_rb2,
    const float* __restrict__ fi_eW1, const float* __restrict__ fi_eb1,
    const float* __restrict__ fi_eW2, const float* __restrict__ fi_eb2,
    const float* __restrict__ fe_rW1, const float* __restrict__ fe_rb1,
    const float* __restrict__ fe_rW2, const float* __restrict__ fe_rb2,
    const float* __restrict__ fe_eW1, const float* __restrict__ fe_eb1,
    const float* __restrict__ fe_eW2, const float* __restrict__ fe_eb2,
    const float* __restrict__ q_inv, const float* __restrict__ k_inv,
    const float* __restrict__ v_inv,
    const float* __restrict__ q_ev, const float* __restrict__ k_ev,
    float* __restrict__ acc_inv, float* __restrict__ acc_ev)
{
    // layer-1 hiddens stored TRANSPOSED: [filter][dim][edge] so layer-2 reads float4 over edges
    __shared__ __align__(16) float s_hidR[2][F_DIM][TE];
    __shared__ __align__(16) float s_hidE[2][F_Q][TE];
    __shared__ __align__(16) float s_rbf[R_DIM][TE];
    __shared__ __align__(16) float s_ei[3][TE];
    __shared__ __align__(16) float s_part[TE][2 * F_DIM];
    __shared__ float s_alpha[TE][8];
    __shared__ float s_c[TE];
    __shared__ int s_snd[TE], s_rcv[TE];

    const int e0g = blockIdx.x * TE;
    const int tid = threadIdx.x;

    // ---- phase 0: stage edge scalars
    if (tid < TE)            s_snd[tid] = senders[e0g + tid];
    else if (tid < 2 * TE)   s_rcv[tid - TE] = receivers[e0g + tid - TE];
    else if (tid < 3 * TE)   s_c[tid - 2 * TE] = cutoffs[e0g + tid - 2 * TE];
    for (int i = tid; i < TE * R_DIM; i += 256) {
        int e = i / R_DIM, k = i - e * R_DIM;
        s_rbf[k][e] = rbf[(size_t)(e0g + e) * R_DIM + k];
    }
    __syncthreads();
    // ev_diff^2 (temp in s_part[e][0..14])
    if (tid < TE * EV_DIM) {
        int e = tid / EV_DIM, i = tid - e * EV_DIM;
        float d = ev_feat[(size_t)s_snd[e] * EV_DIM + i]
                - ev_feat[(size_t)s_rcv[e] * EV_DIM + i];
        s_part[e][i] = d * d;
    }
    __syncthreads();
    if (tid < TE * 3) {
        int e = tid / 3, k = tid - e * 3;
        int i0 = (k == 0) ? 0 : (k == 1) ? 3 : 8;
        int i1 = (k == 0) ? 3 : (k == 1) ? 8 : 15;
        float s = 0.f;
        for (int i = i0; i < i1; ++i) s += s_part[e][i];
        s_ei[k][e] = s;
    }
    __syncthreads();

    // ---- phase 1: layer 1 (hidden = silu(in @ W1 + b1))
    // r-branch: 2 filters x 132 ch x 4 edge-quads = 1056 items
    for (int it = tid; it < 2 * F_DIM * 4; it += 256) {
        int f = it / (F_DIM * 4);
        int rem = it - f * (F_DIM * 4);
        int j = rem >> 2, q = rem & 3;
        const float* W1 = f ? fe_rW1 : fi_rW1;
        const float* b1 = f ? fe_rb1 : fi_rb1;
        float b = b1[j];
        float ax = b, ay = b, az = b, aw = b;
        #pragma unroll 8
        for (int k = 0; k < R_DIM; ++k) {
            float w = W1[k * F_DIM + j];
            float4 r = *(const float4*)&s_rbf[k][q * 4];
            ax += r.x * w; ay += r.y * w; az += r.z * w; aw += r.w * w;
        }
        float4 o; o.x = silu_f(ax); o.y = silu_f(ay); o.z = silu_f(az); o.w = silu_f(aw);
        *(float4*)&s_hidR[f][j][q * 4] = o;
    }
    // e-branch: 2 filters x 33 ch x 4 edge-quads = 264 items
    for (int it = tid; it < 2 * F_Q * 4; it += 256) {
        int f = it / (F_Q * 4);
        int rem = it - f * (F_Q * 4);
        int j = rem >> 2, q = rem & 3;
        const float* W1 = f ? fe_eW1 : fi_eW1;
        const float* b1 = f ? fe_eb1 : fi_eb1;
        float b = b1[j];
        float ax = b, ay = b, az = b, aw = b;
        #pragma unroll
        for (int k = 0; k < 3; ++k) {
            float w = W1[k * F_Q + j];
            float4 r = *(const float4*)&s_ei[k][q * 4];
            ax += r.x * w; ay += r.y * w; az += r.z * w; aw += r.w * w;
        }
        float4 o; o.x = silu_f(ax); o.y = silu_f(ay); o.z = silu_f(az); o.w = silu_f(aw);
        *(float4*)&s_hidE[f][j][q * 4] = o;
    }
    __syncthreads();

    // ---- phase 2: layer 2 + q*k*fw partial products
    // 2 filters x 33 ch-quads x 4 edge-quads = 264 items; 4x4 register tile each
    for (int it = tid; it < 2 * F_Q * 4; it += 256) {
        int f = it / (F_Q * 4);
        int rem = it - f * (F_Q * 4);
        int jq = rem >> 2, q = rem & 3;
        int j0 = jq * 4, eb = q * 4;
        const float* W2  = f ? fe_rW2 : fi_rW2;
        const float* b2  = f ? fe_rb2 : fi_rb2;
        const float* eW2 = f ? fe_eW2 : fi_eW2;
        const float* eb2 = f ? fe_eb2 : fi_eb2;
        float4 bb1 = *(const float4*)&b2[j0];
        float4 bb2 = *(const float4*)&eb2[j0];
        float4 bi; bi.x = bb1.x + bb2.x; bi.y = bb1.y + bb2.y;
        bi.z = bb1.z + bb2.z; bi.w = bb1.w + bb2.w;
        float4 a0 = bi, a1 = bi, a2 = bi, a3 = bi;  // a<e> = fw[j0..j0+3] for edge eb+e
        #pragma unroll 4
        for (int d = 0; d < F_DIM; ++d) {
            float4 w = *(const float4*)&W2[d * F_DIM + j0];
            float4 h = *(const float4*)&s_hidR[f][d][eb];
            a0.x += h.x * w.x; a0.y += h.x * w.y; a0.z += h.x * w.z; a0.w += h.x * w.w;
            a1.x += h.y * w.x; a1.y += h.y * w.y; a1.z += h.y * w.z; a1.w += h.y * w.w;
            a2.x += h.z * w.x; a2.y += h.z * w.y; a2.z += h.z * w.z; a2.w += h.z * w.w;
            a3.x += h.w * w.x; a3.y += h.w * w.y; a3.z += h.w * w.z; a3.w += h.w * w.w;
        }
        #pragma unroll 3
        for (int d = 0; d < F_Q; ++d) {
            float4 w = *(const float4*)&eW2[d * F_DIM + j0];
            float4 h = *(const float4*)&s_hidE[f][d][eb];
            a0.x += h.x * w.x; a0.y += h.x * w.y; a0.z += h.x * w.z; a0.w += h.x * w.w;
            a1.x += h.y * w.x; a1.y += h.y * w.y; a1.z += h.y * w.z; a1.w += h.y * w.w;
            a2.x += h.z * w.x; a2.y += h.z * w.y; a2.z += h.z * w.z; a2.w += h.z * w.w;
            a3.x += h.w * w.x; a3.y += h.w * w.y; a3.z += h.w * w.z; a3.w += h.w * w.w;
        }
        const float* qp = f ? q_ev : q_inv;
        const float* kp = f ? k_ev : k_inv;
        #pragma unroll
        for (int e = 0; e < 4; ++e) {
            int el = eb + e;
            float4 fw = (e == 0) ? a0 : (e == 1) ? a1 : (e == 2) ? a2 : a3;
            float4 qv = *(const float4*)&qp[(size_t)s_rcv[el] * F_DIM + j0];
            float4 kv = *(const float4*)&kp[(size_t)s_snd[el] * F_DIM + j0];
            float4 p;
            p.x = qv.x * kv.x * fw.x; p.y = qv.y * kv.y * fw.y;
            p.z = qv.z * kv.z * fw.z; p.w = qv.w * kv.w * fw.w;
            *(float4*)&s_part[el][f * F_DIM + j0] = p;
        }
    }
    __syncthreads();

    // ---- phase 3: alpha reductions (premultiplied by cutoff)
    if (tid < TE * 7) {
        int e = tid / 7, a = tid - e * 7;
        float s = 0.f;
        if (a < H_INV_N) {
            for (int d = 0; d < D_INV_N; ++d) s += s_part[e][a * D_INV_N + d];
            s_alpha[e][a] = s_c[e] * s * RCP_NORM_INV;
        } else {
            int h = a - H_INV_N;
            for (int d = 0; d < D_EV_N; ++d) s += s_part[e][F_DIM + h * D_EV_N + d];
            s_alpha[e][a] = s_c[e] * s * RCP_NORM_EV;
        }
    }
    __syncthreads();

    // ---- phase 4: scatter messages (atomics)
    for (int it = tid; it < TE * F_Q; it += 256) {   // 528 items: edge x ch-quad
        int e = it / F_Q, jq = it - e * F_Q;
        int j0 = jq * 4;
        int sn = s_snd[e], rn = s_rcv[e];
        float4 v = *(const float4*)&v_inv[(size_t)sn * F_DIM + j0];
        float* dst = acc_inv + (size_t)rn * F_DIM + j0;
        atomicAdd(dst + 0, s_alpha[e][(j0 + 0) / D_INV_N] * v.x);
        atomicAdd(dst + 1, s_alpha[e][(j0 + 1) / D_INV_N] * v.y);
        atomicAdd(dst + 2, s_alpha[e][(j0 + 2) / D_INV_N] * v.z);
        atomicAdd(dst + 3, s_alpha[e][(j0 + 3) / D_INV_N] * v.w);
    }
    if (tid < TE * EV_DIM) {
        int e = tid / EV_DIM, i = tid - e * EV_DIM;
        int seg = (i < 3) ? 0 : (i < 8) ? 1 : 2;
        atomicAdd(&acc_ev[(size_t)s_rcv[e] * EV_DIM + i],
                  s_alpha[e][4 + seg] * sh_vec[(size_t)(e0g + e) * EV_DIM + i]);
    }
}

// ---------------------------------------------------------------------------
// Kernel 3: epilogue — residuals, 135x135 interaction, outputs
// block = 192 threads, 8 nodes/block
// ---------------------------------------------------------------------------
__global__ __launch_bounds__(192) void epilogue_kernel(
    const float* __restrict__ inv_feat, const float* __restrict__ ev_feat,
    const float* __restrict__ acc_inv, const float* __restrict__ acc_ev,
    const float* __restrict__ W_int, const float* __restrict__ b_int,
    float* __restrict__ out0, float* __restrict__ out1)
{
    const int NB = 8;
    __shared__ float s_in[NB][INT_DIM + 1];  // inv1(132) + ev1_inv(3)
    __shared__ float s_ev1[NB][EV_DIM + 1];
    __shared__ float s_b[NB][3];
    int n0 = blockIdx.x * NB;
    int tid = threadIdx.x;
    for (int i = tid; i < NB * F_DIM; i += 192) {
        int nb = i / F_DIM, j = i - nb * F_DIM;
        size_t idx = (size_t)(n0 + nb) * F_DIM + j;
        s_in[nb][j] = inv_feat[idx] + acc_inv[idx];
    }
    for (int i = tid; i < NB * EV_DIM; i += 192) {
        int nb = i / EV_DIM, j = i - nb * EV_DIM;
        size_t idx = (size_t)(n0 + nb) * EV_DIM + j;
        s_ev1[nb][j] = ev_feat[idx] + acc_ev[idx];
    }
    __syncthreads();
    if (tid < NB * 3) {
        int nb = tid / 3, k = tid - nb * 3;
        int i0 = (k == 0) ? 0 : (k == 1) ? 3 : 8;
        int i1 = (k == 0) ? 3 : (k == 1) ? 8 : 15;
        float s = 0.f;
        for (int i = i0; i < i1; ++i) { float v = s_ev1[nb][i]; s += v * v; }
        s_in[nb][F_DIM + k] = s;
    }
    __syncthreads();
    if (tid < INT_DIM) {
        int j = tid;
        float b = b_int[j];
        float acc[NB];
        #pragma unroll
        for (int nb = 0; nb < NB; ++nb) acc[nb] = b;
        for (int i = 0; i < INT_DIM; ++i) {
            float w = W_int[i * INT_DIM + j];
            #pragma unroll
            for (int nb = 0; nb < NB; ++nb) acc[nb] += s_in[nb][i] * w;
        }
        if (j < F_DIM) {
            #pragma unroll
            for (int nb = 0; nb < NB; ++nb)
                out0[(size_t)(n0 + nb) * F_DIM + j] = s_in[nb][j] + acc[nb];
        } else {
            #pragma unroll
            for (int nb = 0; nb < NB; ++nb)
                s_b[nb][j - F_DIM] = acc[nb];
        }
    }
    __syncthreads();
    for (int i = tid; i < NB * EV_DIM; i += 192) {
        int nb = i / EV_DIM, ii = i - nb * EV_DIM;
        int seg = (ii < 3) ? 0 : (ii < 8) ? 1 : 2;
        out1[(size_t)(n0 + nb) * EV_DIM + ii] = s_ev1[nb][ii] * (1.f + s_b[nb][seg]);
    }
}

// ---------------------------------------------------------------------------
extern "C" void kernel_launch(void* const* d_in, const int* in_sizes, int n_in,
                              void* d_out, int out_size, void* d_ws, size_t ws_size,
                              hipStream_t stream)
{
    const float* inv_feat  = (const float*)d_in[0];
    const float* ev_feat   = (const float*)d_in[1];
    const float* rbf       = (const float*)d_in[2];
    const float* sh_vec    = (const float*)d_in[3];
    const float* cutoffs   = (const float*)d_in[4];
    const int*   senders   = (const int*)d_in[5];
    const int*   receivers = (const int*)d_in[6];
    const float* Wq_inv = (const float*)d_in[7];
    const float* Wk_inv = (const float*)d_in[8];
    const float* Wv_inv = (const float*)d_in[9];
    const float* Wq_ev  = (const float*)d_in[10];
    const float* Wk_ev  = (const float*)d_in[11];
    const float* fi_rW1 = (const float*)d_in[12];
    const float* fi_rb1 = (const float*)d_in[13];
    const float* fi_rW2 = (const float*)d_in[14];
    const float* fi_rb2 = (const float*)d_in[15];
    const float* fi_eW1 = (const float*)d_in[16];
    const float* fi_eb1 = (const float*)d_in[17];
    const float* fi_eW2 = (const float*)d_in[18];
    const float* fi_eb2 = (const float*)d_in[19];
    const float* fe_rW1 = (const float*)d_in[20];
    const float* fe_rb1 = (const float*)d_in[21];
    const float* fe_rW2 = (const float*)d_in[22];
    const float* fe_rb2 = (const float*)d_in[23];
    const float* fe_eW1 = (const float*)d_in[24];
    const float* fe_eb1 = (const float*)d_in[25];
    const float* fe_eW2 = (const float*)d_in[26];
    const float* fe_eb2 = (const float*)d_in[27];
    const float* W_int  = (const float*)d_in[28];
    const float* b_int  = (const float*)d_in[29];

    const size_t NF = (size_t)N_NODES * F_DIM;
    float* ws    = (float*)d_ws;
    float* q_inv = ws;
    float* k_inv = ws + 1 * NF;
    float* v_inv = ws + 2 * NF;
    float* q_ev  = ws + 3 * NF;
    float* k_ev  = ws + 4 * NF;
    float* a_inv = ws + 5 * NF;
    float* a_ev  = ws + 6 * NF;

    float* out0 = (float*)d_out;
    float* out1 = out0 + NF;

    // zero the scatter accumulators (ws is poisoned 0xAA before each call)
    hipMemsetAsync(a_inv, 0, (NF + (size_t)N_NODES * EV_DIM) * sizeof(float), stream);

    node_proj_kernel<<<N_NODES / 4, 256, 0, stream>>>(
        inv_feat, Wq_inv, Wk_inv, Wv_inv, Wq_ev, Wk_ev,
        q_inv, k_inv, v_inv, q_ev, k_ev);

    edge_kernel<<<N_EDGES / TE, 256, 0, stream>>>(
        ev_feat, rbf, sh_vec, cutoffs, senders, receivers,
        fi_rW1, fi_rb1, fi_rW2, fi_rb2, fi_eW1, fi_eb1, fi_eW2, fi_eb2,
        fe_rW1, fe_rb1, fe_rW2, fe_rb2, fe_eW1, fe_eb1, fe_eW2, fe_eb2,
        q_inv, k_inv, v_inv, q_ev, k_ev,
        a_inv, a_ev);

    epilogue_kernel<<<N_NODES / 8, 192, 0, stream>>>(
        inv_feat, ev_feat, a_inv, a_ev, W_int, b_int, out0, out1);
}

// Round 3
// 1668.703 us; speedup vs baseline: 1.0750x; 1.0750x over previous
//
#include <hip/hip_runtime.h>
#include <type_traits>

#define N_NODES 50000
#define N_EDGES 400000
#define R_DIM   32
#define F_DIM   132
#define EV_DIM  15
#define F_Q     33
#define INT_DIM 135
#define TE      32      // edges per block in edge kernel

#define RCP_NORM_INV 0.17407765595569785f  // 1/sqrt(33)
#define RCP_NORM_EV  0.15075567228888181f  // 1/sqrt(44)

typedef __attribute__((ext_vector_type(8))) short bf16x8;
typedef __attribute__((ext_vector_type(4))) float f32x4;

__device__ __forceinline__ float silu_f(float x) { return x / (1.f + __expf(-x)); }

__device__ __forceinline__ unsigned short f2bf(float x) {
    union { float f; unsigned u; } c; c.f = x;
    unsigned r = c.u + 0x7FFFu + ((c.u >> 16) & 1u);  // RNE
    return (unsigned short)(r >> 16);
}

// ---------------------------------------------------------------------------
// Prep: swizzle both filters' layer-2 weights into MFMA b-frag order (bf16).
// Combined K layout: k<132 = rW2 rows, 132..164 = eW2 rows, 165..191 = zero.
// N padded 132->144. Frag value(f,kc,nt,lane,j) = W2comb[f][kc*32+(l>>4)*8+j][nt*16+(l&15)]
// Also biasC[f][144] = rb2+eb2 (fp32).
// ---------------------------------------------------------------------------
__global__ __launch_bounds__(256) void prep_kernel(
    const float* __restrict__ fi_rW2, const float* __restrict__ fi_eW2,
    const float* __restrict__ fe_rW2, const float* __restrict__ fe_eW2,
    const float* __restrict__ fi_rb2, const float* __restrict__ fi_eb2,
    const float* __restrict__ fe_rb2, const float* __restrict__ fe_eb2,
    unsigned short* __restrict__ Bfrag, float* __restrict__ biasC)
{
    int t = blockIdx.x * 256 + threadIdx.x;
    if (t < 6912) {
        int l = t & 63, idx = t >> 6;
        int nt = idx % 9, kc = (idx / 9) % 6, f = idx / 54;
        const float* rW2 = f ? fe_rW2 : fi_rW2;
        const float* eW2 = f ? fe_eW2 : fi_eW2;
        int n = nt * 16 + (l & 15);
        unsigned short v[8];
        #pragma unroll
        for (int j = 0; j < 8; ++j) {
            int k = kc * 32 + (l >> 4) * 8 + j;
            float w = 0.f;
            if (n < F_DIM) {
                if (k < F_DIM) w = rW2[k * F_DIM + n];
                else if (k < F_DIM + F_Q) w = eW2[(k - F_DIM) * F_DIM + n];
            }
            v[j] = f2bf(w);
        }
        *(uint4*)&Bfrag[(size_t)t * 8] = *(const uint4*)v;
    }
    if (blockIdx.x == 0) {
        for (int i = threadIdx.x; i < 288; i += 256) {   // FIX: 288 > 256, loop
            int f = i / 144, n = i % 144;
            const float* rb2 = f ? fe_rb2 : fi_rb2;
            const float* eb2 = f ? fe_eb2 : fi_eb2;
            biasC[i] = (n < F_DIM) ? (rb2[n] + eb2[n]) : 0.f;
        }
    }
}

// ---------------------------------------------------------------------------
// Kernel 1: per-node projections, 8 nodes/block (512 thr) to amortize weights
// ---------------------------------------------------------------------------
__global__ __launch_bounds__(512) void node_proj_kernel(
    const float* __restrict__ x,
    const float* __restrict__ Wq_inv, const float* __restrict__ Wk_inv,
    const float* __restrict__ Wv_inv,
    const float* __restrict__ Wq_ev, const float* __restrict__ Wk_ev,
    float* __restrict__ q_inv, float* __restrict__ k_inv, float* __restrict__ v_inv,
    float* __restrict__ q_ev, float* __restrict__ k_ev)
{
    __shared__ float xs[8][F_DIM];
    int node0 = blockIdx.x * 8;
    for (int i = threadIdx.x; i < 8 * F_DIM; i += 512) {
        int nb = i / F_DIM, j = i - nb * F_DIM;
        xs[nb][j] = x[(size_t)(node0 + nb) * F_DIM + j];
    }
    __syncthreads();
    int nb = threadIdx.x >> 6;
    int lane = threadIdx.x & 63;
    int n = node0 + nb;
    const float* xr = xs[nb];
    for (int o = lane; o < 5 * F_DIM; o += 64) {
        int arr = o / F_DIM, ch = o - arr * F_DIM;
        float acc = 0.f;
        if (arr < 3) {
            int h = ch / 33, e = ch - h * 33;
            const float* W = (arr == 0 ? Wq_inv : (arr == 1 ? Wk_inv : Wv_inv))
                             + h * 33 * 33 + e;
            const float* xh = xr + h * 33;
            #pragma unroll
            for (int d = 0; d < 33; ++d) acc += xh[d] * W[d * 33];
            if (arr < 2) acc = silu_f(acc);
            float* dst = (arr == 0 ? q_inv : (arr == 1 ? k_inv : v_inv));
            dst[(size_t)n * F_DIM + ch] = acc;
        } else {
            int h = ch / 44, e = ch - h * 44;
            const float* W = (arr == 3 ? Wq_ev : Wk_ev) + h * 44 * 44 + e;
            const float* xh = xr + h * 44;
            #pragma unroll
            for (int d = 0; d < 44; ++d) acc += xh[d] * W[d * 44];
            acc = silu_f(acc);
            float* dst = (arr == 3 ? q_ev : k_ev);
            dst[(size_t)n * F_DIM + ch] = acc;
        }
    }
}

// ---------------------------------------------------------------------------
// Kernel 2: edge filters (layer1 VALU fp32, layer2 bf16 MFMA) + attention + scatter
// 256 thr = 4 waves; wave = (filter, M-tile of 16 edges); TE=32 edges/block
// ---------------------------------------------------------------------------
__global__ __launch_bounds__(256) void edge_kernel(
    const float* __restrict__ ev_feat, const float* __restrict__ rbf,
    const float* __restrict__ sh_vec, const float* __restrict__ cutoffs,
    const int* __restrict__ senders, const int* __restrict__ receivers,
    const float* __restrict__ fi_rW1, const float* __restrict__ fi_rb1,
    const float* __restrict__ fi_eW1, const float* __restrict__ fi_eb1,
    const float* __restrict__ fe_rW1, const float* __restrict__ fe_rb1,
    const float* __restrict__ fe_eW1, const float* __restrict__ fe_eb1,
    const unsigned short* __restrict__ Bfrag, const float* __restrict__ biasC,
    const float* __restrict__ q_inv, const float* __restrict__ k_inv,
    const float* __restrict__ v_inv,
    const float* __restrict__ q_ev, const float* __restrict__ k_ev,
    float* __restrict__ acc_inv, float* __restrict__ acc_ev)
{
    // hidden rows: [filter][edge][200 bf16]; cols 0..131 = hidR, 132..164 = hidE,
    // 165..191 = zero (K padding), 192..199 = row pad (never read)
    __shared__ __align__(16) unsigned short s_hid[2][TE][200];
    __shared__ float s_rbf[R_DIM][TE];      // transposed for layer-1 reads
    __shared__ float s_ei[3][TE];
    __shared__ float s_d2[TE][16];
    __shared__ float s_alpha[TE][8];        // cutoff*alpha/sqrt(D), slots 0-3 inv, 4-6 ev
    __shared__ float s_c[TE];
    __shared__ int s_snd[TE], s_rcv[TE];

    const int e0g = blockIdx.x * TE;
    const int tid = threadIdx.x;

    // ---- P0: stage edge meta + rbf; zero hid K-pad region (words 82..99/row)
    if (tid < TE)            s_snd[tid] = senders[e0g + tid];
    else if (tid < 2 * TE)   s_rcv[tid - TE] = receivers[e0g + tid - TE];
    else if (tid < 3 * TE)   s_c[tid - 2 * TE] = cutoffs[e0g + tid - 2 * TE];
    for (int i = tid; i < TE * R_DIM; i += 256) {
        int e = i >> 5, k = i & 31;
        s_rbf[k][e] = rbf[(size_t)(e0g + e) * R_DIM + k];
    }
    {
        unsigned* hz = (unsigned*)s_hid;
        for (int i = tid; i < 64 * 18; i += 256) {
            int row = i / 18, w = 82 + (i - row * 18);
            hz[row * 100 + w] = 0u;
        }
    }
    __syncthreads();
    for (int i = tid; i < TE * EV_DIM; i += 256) {   // FIX: 480 > 256, loop
        int e = i / EV_DIM, j = i - e * EV_DIM;
        float d = ev_feat[(size_t)s_snd[e] * EV_DIM + j]
                - ev_feat[(size_t)s_rcv[e] * EV_DIM + j];
        s_d2[e][j] = d * d;
    }
    __syncthreads();
    if (tid < TE * 3) {
        int e = tid / 3, k2 = tid - e * 3;
        int i0 = (k2 == 0) ? 0 : (k2 == 1) ? 3 : 8;
        int i1 = (k2 == 0) ? 3 : (k2 == 1) ? 8 : 15;
        float s = 0.f;
        for (int i = i0; i < i1; ++i) s += s_d2[e][i];
        s_ei[k2][e] = s;
    }
    __syncthreads();

    // ---- P1: layer 1 (fp32 VALU) -> bf16 hid rows
    // r-branch: item = (filter, col-quad jq<33, edge) : 2112 items
    for (int it = tid; it < 2 * F_Q * TE; it += 256) {
        int f = it >= F_Q * TE;
        int rem = it - f * (F_Q * TE);
        int jq = rem >> 5, e = rem & 31;
        int j0 = jq * 4;
        const float* W1 = f ? fe_rW1 : fi_rW1;
        const float* b1 = f ? fe_rb1 : fi_rb1;
        float4 a = *(const float4*)&b1[j0];
        #pragma unroll 8
        for (int k = 0; k < R_DIM; ++k) {
            float r = s_rbf[k][e];
            float4 w = *(const float4*)&W1[k * F_DIM + j0];
            a.x += r * w.x; a.y += r * w.y; a.z += r * w.z; a.w += r * w.w;
        }
        unsigned short o[4] = { f2bf(silu_f(a.x)), f2bf(silu_f(a.y)),
                                f2bf(silu_f(a.z)), f2bf(silu_f(a.w)) };
        *(uint2*)&s_hid[f][e][j0] = *(const uint2*)o;
    }
    // e-branch: 8 col-quads (scalar weight loads; W1 rows not 16B aligned)
    for (int it = tid; it < 2 * 8 * TE; it += 256) {
        int f = it >= 8 * TE;
        int rem = it - f * (8 * TE);
        int jq = rem >> 5, e = rem & 31;
        int j0 = jq * 4;
        const float* W1 = f ? fe_eW1 : fi_eW1;
        const float* b1 = f ? fe_eb1 : fi_eb1;
        float a0 = b1[j0], a1 = b1[j0+1], a2 = b1[j0+2], a3 = b1[j0+3];
        #pragma unroll
        for (int k = 0; k < 3; ++k) {
            float r = s_ei[k][e];
            const float* wr = &W1[k * F_Q + j0];
            a0 += r * wr[0]; a1 += r * wr[1]; a2 += r * wr[2]; a3 += r * wr[3];
        }
        unsigned short o[4] = { f2bf(silu_f(a0)), f2bf(silu_f(a1)),
                                f2bf(silu_f(a2)), f2bf(silu_f(a3)) };
        *(uint2*)&s_hid[f][e][F_DIM + j0] = *(const uint2*)o;
    }
    if (tid < 2 * TE) {  // remainder col 32 of e-branch (64 <= 256, single-shot ok)
        int f = tid >= TE, e = tid & 31;
        const float* W1 = f ? fe_eW1 : fi_eW1;
        const float* b1 = f ? fe_eb1 : fi_eb1;
        float a = b1[32];
        #pragma unroll
        for (int k = 0; k < 3; ++k) a += s_ei[k][e] * W1[k * F_Q + 32];
        s_hid[f][e][F_DIM + 32] = f2bf(silu_f(a));
    }
    __syncthreads();

    // ---- P2: layer-2 MFMA + fused alpha epilogue (per-wave)
    const int wv = tid >> 6, l = tid & 63;
    const int f = wv & 1, m0 = (wv >> 1) * 16;
    const int l15 = l & 15, g4 = l >> 4;

    bf16x8 afr[6];
    {
        const unsigned short* hrow = &s_hid[f][m0 + l15][0];
        #pragma unroll
        for (int kc = 0; kc < 6; ++kc)
            afr[kc] = *(const bf16x8*)&hrow[kc * 32 + g4 * 8];
    }
    const unsigned short* Bf = Bfrag + (size_t)f * 54 * 512 + (size_t)l * 8;

    int rcvr[4], sndr[4];
    #pragma unroll
    for (int r = 0; r < 4; ++r) {
        int e = m0 + g4 * 4 + r;
        rcvr[r] = s_rcv[e]; sndr[r] = s_snd[e];
    }

    auto run = [&](auto FC) {
        constexpr int F_ = decltype(FC)::value;
        constexpr int NH = F_ ? 3 : 4;
        constexpr int DD = F_ ? 44 : 33;
        const float* qp = F_ ? q_ev : q_inv;
        const float* kp = F_ ? k_ev : k_inv;
        float part[NH][4];
        #pragma unroll
        for (int h = 0; h < NH; ++h)
            #pragma unroll
            for (int r = 0; r < 4; ++r) part[h][r] = 0.f;

        #pragma unroll
        for (int nt = 0; nt < 9; ++nt) {
            f32x4 acc = {0.f, 0.f, 0.f, 0.f};
            #pragma unroll
            for (int kc = 0; kc < 6; ++kc) {
                bf16x8 bfr = *(const bf16x8*)(Bf + (size_t)(kc * 9 + nt) * 512);
                acc = __builtin_amdgcn_mfma_f32_16x16x32_bf16(afr[kc], bfr, acc, 0, 0, 0);
            }
            const int n = nt * 16 + l15;
            const bool nvalid = (n < F_DIM);
            const float bias = biasC[F_ * 144 + n];
            int h0v = (nt * 16) / DD;            // folds to constants after unroll
            int bsp = (h0v + 1) * DD - nt * 16;  // lanes l15 < bsp -> head h0v
            #pragma unroll
            for (int r = 0; r < 4; ++r) {
                float p = 0.f;
                if (nvalid) {
                    float fw = acc[r] + bias;
                    float qv = qp[(size_t)rcvr[r] * F_DIM + n];
                    float kv = kp[(size_t)sndr[r] * F_DIM + n];
                    p = qv * kv * fw;
                }
                if (bsp >= 16) {
                    part[h0v][r] += p;
                } else {
                    float plo = (l15 < bsp) ? p : 0.f;
                    part[h0v][r] += plo;
                    if (h0v + 1 < NH) part[h0v + 1][r] += (p - plo);
                }
            }
        }
        // 16-lane reductions -> s_alpha
        #pragma unroll
        for (int h = 0; h < NH; ++h) {
            #pragma unroll
            for (int r = 0; r < 4; ++r) {
                float v = part[h][r];
                v += __shfl_xor(v, 1);
                v += __shfl_xor(v, 2);
                v += __shfl_xor(v, 4);
                v += __shfl_xor(v, 8);
                if (l15 == 0) {
                    int e = m0 + g4 * 4 + r;
                    s_alpha[e][F_ ? 4 + h : h] =
                        v * s_c[e] * (F_ ? RCP_NORM_EV : RCP_NORM_INV);
                }
            }
        }
    };
    if (f == 0) run(std::integral_constant<int, 0>{});
    else        run(std::integral_constant<int, 1>{});
    __syncthreads();

    // ---- P3: scatter (atomics)
    for (int it = tid; it < TE * F_Q; it += 256) {
        int e = it / F_Q, jq = it - e * F_Q;
        int j0 = jq * 4;
        int sn = s_snd[e], rn = s_rcv[e];
        float4 v = *(const float4*)&v_inv[(size_t)sn * F_DIM + j0];
        float* dst = acc_inv + (size_t)rn * F_DIM + j0;
        atomicAdd(dst + 0, s_alpha[e][(j0 + 0) / 33] * v.x);
        atomicAdd(dst + 1, s_alpha[e][(j0 + 1) / 33] * v.y);
        atomicAdd(dst + 2, s_alpha[e][(j0 + 2) / 33] * v.z);
        atomicAdd(dst + 3, s_alpha[e][(j0 + 3) / 33] * v.w);
    }
    for (int i = tid; i < TE * EV_DIM; i += 256) {   // FIX: 480 > 256, loop
        int e = i / EV_DIM, j = i - e * EV_DIM;
        int seg = (j < 3) ? 0 : (j < 8) ? 1 : 2;
        atomicAdd(&acc_ev[(size_t)s_rcv[e] * EV_DIM + j],
                  s_alpha[e][4 + seg] * sh_vec[(size_t)(e0g + e) * EV_DIM + j]);
    }
}

// ---------------------------------------------------------------------------
// Kernel 3: epilogue — residuals, 135x135 interaction, outputs
// ---------------------------------------------------------------------------
__global__ __launch_bounds__(192) void epilogue_kernel(
    const float* __restrict__ inv_feat, const float* __restrict__ ev_feat,
    const float* __restrict__ acc_inv, const float* __restrict__ acc_ev,
    const float* __restrict__ W_int, const float* __restrict__ b_int,
    float* __restrict__ out0, float* __restrict__ out1)
{
    const int NB = 8;
    __shared__ float s_in[NB][INT_DIM + 1];
    __shared__ float s_ev1[NB][EV_DIM + 1];
    __shared__ float s_b[NB][3];
    int n0 = blockIdx.x * NB;
    int tid = threadIdx.x;
    for (int i = tid; i < NB * F_DIM; i += 192) {
        int nb = i / F_DIM, j = i - nb * F_DIM;
        size_t idx = (size_t)(n0 + nb) * F_DIM + j;
        s_in[nb][j] = inv_feat[idx] + acc_inv[idx];
    }
    for (int i = tid; i < NB * EV_DIM; i += 192) {
        int nb = i / EV_DIM, j = i - nb * EV_DIM;
        size_t idx = (size_t)(n0 + nb) * EV_DIM + j;
        s_ev1[nb][j] = ev_feat[idx] + acc_ev[idx];
    }
    __syncthreads();
    if (tid < NB * 3) {
        int nb = tid / 3, k = tid - nb * 3;
        int i0 = (k == 0) ? 0 : (k == 1) ? 3 : 8;
        int i1 = (k == 0) ? 3 : (k == 1) ? 8 : 15;
        float s = 0.f;
        for (int i = i0; i < i1; ++i) { float v = s_ev1[nb][i]; s += v * v; }
        s_in[nb][F_DIM + k] = s;
    }
    __syncthreads();
    if (tid < INT_DIM) {
        int j = tid;
        float b = b_int[j];
        float acc[NB];
        #pragma unroll
        for (int nb = 0; nb < NB; ++nb) acc[nb] = b;
        for (int i = 0; i < INT_DIM; ++i) {
            float w = W_int[i * INT_DIM + j];
            #pragma unroll
            for (int nb = 0; nb < NB; ++nb) acc[nb] += s_in[nb][i] * w;
        }
        if (j < F_DIM) {
            #pragma unroll
            for (int nb = 0; nb < NB; ++nb)
                out0[(size_t)(n0 + nb) * F_DIM + j] = s_in[nb][j] + acc[nb];
        } else {
            #pragma unroll
            for (int nb = 0; nb < NB; ++nb)
                s_b[nb][j - F_DIM] = acc[nb];
        }
    }
    __syncthreads();
    for (int i = tid; i < NB * EV_DIM; i += 192) {
        int nb = i / EV_DIM, ii = i - nb * EV_DIM;
        int seg = (ii < 3) ? 0 : (ii < 8) ? 1 : 2;
        out1[(size_t)(n0 + nb) * EV_DIM + ii] = s_ev1[nb][ii] * (1.f + s_b[nb][seg]);
    }
}

// ---------------------------------------------------------------------------
extern "C" void kernel_launch(void* const* d_in, const int* in_sizes, int n_in,
                              void* d_out, int out_size, void* d_ws, size_t ws_size,
                              hipStream_t stream)
{
    const float* inv_feat  = (const float*)d_in[0];
    const float* ev_feat   = (const float*)d_in[1];
    const float* rbf       = (const float*)d_in[2];
    const float* sh_vec    = (const float*)d_in[3];
    const float* cutoffs   = (const float*)d_in[4];
    const int*   senders   = (const int*)d_in[5];
    const int*   receivers = (const int*)d_in[6];
    const float* Wq_inv = (const float*)d_in[7];
    const float* Wk_inv = (const float*)d_in[8];
    const float* Wv_inv = (const float*)d_in[9];
    const float* Wq_ev  = (const float*)d_in[10];
    const float* Wk_ev  = (const float*)d_in[11];
    const float* fi_rW1 = (const float*)d_in[12];
    const float* fi_rb1 = (const float*)d_in[13];
    const float* fi_rW2 = (const float*)d_in[14];
    const float* fi_rb2 = (const float*)d_in[15];
    const float* fi_eW1 = (const float*)d_in[16];
    const float* fi_eb1 = (const float*)d_in[17];
    const float* fi_eW2 = (const float*)d_in[18];
    const float* fi_eb2 = (const float*)d_in[19];
    const float* fe_rW1 = (const float*)d_in[20];
    const float* fe_rb1 = (const float*)d_in[21];
    const float* fe_rW2 = (const float*)d_in[22];
    const float* fe_rb2 = (const float*)d_in[23];
    const float* fe_eW1 = (const float*)d_in[24];
    const float* fe_eb1 = (const float*)d_in[25];
    const float* fe_eW2 = (const float*)d_in[26];
    const float* fe_eb2 = (const float*)d_in[27];
    const float* W_int  = (const float*)d_in[28];
    const float* b_int  = (const float*)d_in[29];

    const size_t NF  = (size_t)N_NODES * F_DIM;
    const size_t NEV = (size_t)N_NODES * EV_DIM;
    float* ws    = (float*)d_ws;
    float* q_inv = ws;
    float* k_inv = ws + 1 * NF;
    float* v_inv = ws + 2 * NF;
    float* q_ev  = ws + 3 * NF;
    float* k_ev  = ws + 4 * NF;
    float* a_inv = ws + 5 * NF;
    float* a_ev  = ws + 6 * NF;
    unsigned short* Bfrag = (unsigned short*)(ws + 6 * NF + NEV);
    float* biasC = (float*)(Bfrag + 55296);

    float* out0 = (float*)d_out;
    float* out1 = out0 + NF;

    hipMemsetAsync(a_inv, 0, (NF + NEV) * sizeof(float), stream);

    prep_kernel<<<27, 256, 0, stream>>>(
        fi_rW2, fi_eW2, fe_rW2, fe_eW2,
        fi_rb2, fi_eb2, fe_rb2, fe_eb2, Bfrag, biasC);

    node_proj_kernel<<<N_NODES / 8, 512, 0, stream>>>(
        inv_feat, Wq_inv, Wk_inv, Wv_inv, Wq_ev, Wk_ev,
        q_inv, k_inv, v_inv, q_ev, k_ev);

    edge_kernel<<<N_EDGES / TE, 256, 0, stream>>>(
        ev_feat, rbf, sh_vec, cutoffs, senders, receivers,
        fi_rW1, fi_rb1, fi_eW1, fi_eb1,
        fe_rW1, fe_rb1, fe_eW1, fe_eb1,
        Bfrag, biasC,
        q_inv, k_inv, v_inv, q_ev, k_ev,
        a_inv, a_ev);

    epilogue_kernel<<<N_NODES / 8, 192, 0, stream>>>(
        inv_feat, ev_feat, a_inv, a_ev, W_int, b_int, out0, out1);
}

// Round 4
// 1498.914 us; speedup vs baseline: 1.1967x; 1.1133x over previous
//
#include <hip/hip_runtime.h>
#include <type_traits>

#define N_NODES 50000
#define N_EDGES 400000
#define R_DIM   32
#define F_DIM   132
#define EV_DIM  15
#define F_Q     33
#define INT_DIM 135
#define TE      32      // edges per block in K_a

#define RCP_NORM_INV 0.17407765595569785f  // 1/sqrt(33)
#define RCP_NORM_EV  0.15075567228888181f  // 1/sqrt(44)

typedef __attribute__((ext_vector_type(8))) short bf16x8;
typedef __attribute__((ext_vector_type(4))) float f32x4;

__device__ __forceinline__ float silu_f(float x) { return x / (1.f + __expf(-x)); }

__device__ __forceinline__ unsigned short f2bf(float x) {
    union { float f; unsigned u; } c; c.f = x;
    unsigned r = c.u + 0x7FFFu + ((c.u >> 16) & 1u);  // RNE
    return (unsigned short)(r >> 16);
}

// ---------------------------------------------------------------------------
// Prep: swizzle layer-2 weights into MFMA b-frag order (bf16). See R2 notes.
// ---------------------------------------------------------------------------
__global__ __launch_bounds__(256) void prep_kernel(
    const float* __restrict__ fi_rW2, const float* __restrict__ fi_eW2,
    const float* __restrict__ fe_rW2, const float* __restrict__ fe_eW2,
    const float* __restrict__ fi_rb2, const float* __restrict__ fi_eb2,
    const float* __restrict__ fe_rb2, const float* __restrict__ fe_eb2,
    unsigned short* __restrict__ Bfrag, float* __restrict__ biasC)
{
    int t = blockIdx.x * 256 + threadIdx.x;
    if (t < 6912) {
        int l = t & 63, idx = t >> 6;
        int nt = idx % 9, kc = (idx / 9) % 6, f = idx / 54;
        const float* rW2 = f ? fe_rW2 : fi_rW2;
        const float* eW2 = f ? fe_eW2 : fi_eW2;
        int n = nt * 16 + (l & 15);
        unsigned short v[8];
        #pragma unroll
        for (int j = 0; j < 8; ++j) {
            int k = kc * 32 + (l >> 4) * 8 + j;
            float w = 0.f;
            if (n < F_DIM) {
                if (k < F_DIM) w = rW2[k * F_DIM + n];
                else if (k < F_DIM + F_Q) w = eW2[(k - F_DIM) * F_DIM + n];
            }
            v[j] = f2bf(w);
        }
        *(uint4*)&Bfrag[(size_t)t * 8] = *(const uint4*)v;
    }
    if (blockIdx.x == 0) {
        for (int i = threadIdx.x; i < 288; i += 256) {
            int f = i / 144, n = i % 144;
            const float* rb2 = f ? fe_rb2 : fi_rb2;
            const float* eb2 = f ? fe_eb2 : fi_eb2;
            biasC[i] = (n < F_DIM) ? (rb2[n] + eb2[n]) : 0.f;
        }
    }
}

// ---------------------------------------------------------------------------
// CSR build: histogram -> single-block scan -> scatter permutation
// ---------------------------------------------------------------------------
__global__ __launch_bounds__(256) void hist_kernel(
    const int* __restrict__ receivers, int* __restrict__ cnt)
{
    int i = blockIdx.x * 256 + threadIdx.x;
    if (i < N_EDGES) atomicAdd(&cnt[receivers[i]], 1);
}

__global__ __launch_bounds__(1024) void scan_kernel(
    const int* __restrict__ cnt, int* __restrict__ off, int* __restrict__ cursor)
{
    __shared__ int sums[1024];
    const int CHUNK = 49;  // 1024*49 = 50176 >= 50000
    int t = threadIdx.x;
    int base = t * CHUNK;
    int s = 0;
    for (int i = 0; i < CHUNK; ++i) {
        int idx = base + i;
        if (idx < N_NODES) s += cnt[idx];
    }
    sums[t] = s;
    __syncthreads();
    for (int d = 1; d < 1024; d <<= 1) {
        int v = (t >= d) ? sums[t - d] : 0;
        __syncthreads();
        sums[t] += v;
        __syncthreads();
    }
    int run = (t == 0) ? 0 : sums[t - 1];
    for (int i = 0; i < CHUNK; ++i) {
        int idx = base + i;
        if (idx < N_NODES) {
            off[idx] = run; cursor[idx] = run;
            run += cnt[idx];
        }
    }
    if (t == 0) off[N_NODES] = N_EDGES;
}

__global__ __launch_bounds__(256) void scatter_kernel(
    const int* __restrict__ receivers, int* __restrict__ cursor,
    int* __restrict__ perm)
{
    int i = blockIdx.x * 256 + threadIdx.x;
    if (i < N_EDGES) {
        int pos = atomicAdd(&cursor[receivers[i]], 1);
        perm[pos] = i;
    }
}

// ---------------------------------------------------------------------------
// Kernel 1: per-node projections, 8 nodes/block
// ---------------------------------------------------------------------------
__global__ __launch_bounds__(512) void node_proj_kernel(
    const float* __restrict__ x,
    const float* __restrict__ Wq_inv, const float* __restrict__ Wk_inv,
    const float* __restrict__ Wv_inv,
    const float* __restrict__ Wq_ev, const float* __restrict__ Wk_ev,
    float* __restrict__ q_inv, float* __restrict__ k_inv, float* __restrict__ v_inv,
    float* __restrict__ q_ev, float* __restrict__ k_ev)
{
    __shared__ float xs[8][F_DIM];
    int node0 = blockIdx.x * 8;
    for (int i = threadIdx.x; i < 8 * F_DIM; i += 512) {
        int nb = i / F_DIM, j = i - nb * F_DIM;
        xs[nb][j] = x[(size_t)(node0 + nb) * F_DIM + j];
    }
    __syncthreads();
    int nb = threadIdx.x >> 6;
    int lane = threadIdx.x & 63;
    int n = node0 + nb;
    const float* xr = xs[nb];
    for (int o = lane; o < 5 * F_DIM; o += 64) {
        int arr = o / F_DIM, ch = o - arr * F_DIM;
        float acc = 0.f;
        if (arr < 3) {
            int h = ch / 33, e = ch - h * 33;
            const float* W = (arr == 0 ? Wq_inv : (arr == 1 ? Wk_inv : Wv_inv))
                             + h * 33 * 33 + e;
            const float* xh = xr + h * 33;
            #pragma unroll
            for (int d = 0; d < 33; ++d) acc += xh[d] * W[d * 33];
            if (arr < 2) acc = silu_f(acc);
            float* dst = (arr == 0 ? q_inv : (arr == 1 ? k_inv : v_inv));
            dst[(size_t)n * F_DIM + ch] = acc;
        } else {
            int h = ch / 44, e = ch - h * 44;
            const float* W = (arr == 3 ? Wq_ev : Wk_ev) + h * 44 * 44 + e;
            const float* xh = xr + h * 44;
            #pragma unroll
            for (int d = 0; d < 44; ++d) acc += xh[d] * W[d * 44];
            acc = silu_f(acc);
            float* dst = (arr == 3 ? q_ev : k_ev);
            dst[(size_t)n * F_DIM + ch] = acc;
        }
    }
}

// ---------------------------------------------------------------------------
// K_a: per-edge filters + alpha (CSR position order). NO fp atomics.
// Writes galpha[pos*8 + {0..6}] and gsnd[pos].
// ---------------------------------------------------------------------------
__global__ __launch_bounds__(256) void edge_alpha_kernel(
    const float* __restrict__ ev_feat, const float* __restrict__ rbf,
    const float* __restrict__ cutoffs,
    const int* __restrict__ senders, const int* __restrict__ receivers,
    const int* __restrict__ perm,
    const float* __restrict__ fi_rW1, const float* __restrict__ fi_rb1,
    const float* __restrict__ fi_eW1, const float* __restrict__ fi_eb1,
    const float* __restrict__ fe_rW1, const float* __restrict__ fe_rb1,
    const float* __restrict__ fe_eW1, const float* __restrict__ fe_eb1,
    const unsigned short* __restrict__ Bfrag, const float* __restrict__ biasC,
    const float* __restrict__ q_inv, const float* __restrict__ k_inv,
    const float* __restrict__ q_ev, const float* __restrict__ k_ev,
    float* __restrict__ galpha, int* __restrict__ gsnd)
{
    __shared__ __align__(16) unsigned short s_hid[2][TE][200];
    __shared__ float s_rbf[R_DIM][TE];
    __shared__ float s_ei[3][TE];
    __shared__ float s_d2[TE][16];
    __shared__ float s_c[TE];
    __shared__ int s_snd[TE], s_rcv[TE], s_eid[TE];

    const int e0g = blockIdx.x * TE;
    const int tid = threadIdx.x;

    // ---- P0a: edge meta via CSR perm
    if (tid < TE) {
        int eid = perm[e0g + tid];
        s_eid[tid] = eid;
        int sn = senders[eid], rc = receivers[eid];
        s_snd[tid] = sn; s_rcv[tid] = rc;
        s_c[tid] = cutoffs[eid];
        gsnd[e0g + tid] = sn;
    }
    __syncthreads();
    // ---- P0b: rbf gather (row-contiguous), hid K-pad zero, ev_diff^2
    for (int i = tid; i < TE * R_DIM; i += 256) {
        int e = i >> 5, k = i & 31;
        s_rbf[k][e] = rbf[(size_t)s_eid[e] * R_DIM + k];
    }
    {
        unsigned* hz = (unsigned*)s_hid;
        for (int i = tid; i < 64 * 18; i += 256) {
            int row = i / 18, w = 82 + (i - row * 18);
            hz[row * 100 + w] = 0u;
        }
    }
    for (int i = tid; i < TE * EV_DIM; i += 256) {
        int e = i / EV_DIM, j = i - e * EV_DIM;
        float d = ev_feat[(size_t)s_snd[e] * EV_DIM + j]
                - ev_feat[(size_t)s_rcv[e] * EV_DIM + j];
        s_d2[e][j] = d * d;
    }
    __syncthreads();
    if (tid < TE * 3) {
        int e = tid / 3, k2 = tid - e * 3;
        int i0 = (k2 == 0) ? 0 : (k2 == 1) ? 3 : 8;
        int i1 = (k2 == 0) ? 3 : (k2 == 1) ? 8 : 15;
        float s = 0.f;
        for (int i = i0; i < i1; ++i) s += s_d2[e][i];
        s_ei[k2][e] = s;
    }
    __syncthreads();

    // ---- P1: layer 1 (fp32 VALU) -> bf16 hid rows
    for (int it = tid; it < 2 * F_Q * TE; it += 256) {
        int f = it >= F_Q * TE;
        int rem = it - f * (F_Q * TE);
        int jq = rem >> 5, e = rem & 31;
        int j0 = jq * 4;
        const float* W1 = f ? fe_rW1 : fi_rW1;
        const float* b1 = f ? fe_rb1 : fi_rb1;
        float4 a = *(const float4*)&b1[j0];
        #pragma unroll 8
        for (int k = 0; k < R_DIM; ++k) {
            float r = s_rbf[k][e];
            float4 w = *(const float4*)&W1[k * F_DIM + j0];
            a.x += r * w.x; a.y += r * w.y; a.z += r * w.z; a.w += r * w.w;
        }
        unsigned short o[4] = { f2bf(silu_f(a.x)), f2bf(silu_f(a.y)),
                                f2bf(silu_f(a.z)), f2bf(silu_f(a.w)) };
        *(uint2*)&s_hid[f][e][j0] = *(const uint2*)o;
    }
    for (int it = tid; it < 2 * 8 * TE; it += 256) {
        int f = it >= 8 * TE;
        int rem = it - f * (8 * TE);
        int jq = rem >> 5, e = rem & 31;
        int j0 = jq * 4;
        const float* W1 = f ? fe_eW1 : fi_eW1;
        const float* b1 = f ? fe_eb1 : fi_eb1;
        float a0 = b1[j0], a1 = b1[j0+1], a2 = b1[j0+2], a3 = b1[j0+3];
        #pragma unroll
        for (int k = 0; k < 3; ++k) {
            float r = s_ei[k][e];
            const float* wr = &W1[k * F_Q + j0];
            a0 += r * wr[0]; a1 += r * wr[1]; a2 += r * wr[2]; a3 += r * wr[3];
        }
        unsigned short o[4] = { f2bf(silu_f(a0)), f2bf(silu_f(a1)),
                                f2bf(silu_f(a2)), f2bf(silu_f(a3)) };
        *(uint2*)&s_hid[f][e][F_DIM + j0] = *(const uint2*)o;
    }
    if (tid < 2 * TE) {
        int f = tid >= TE, e = tid & 31;
        const float* W1 = f ? fe_eW1 : fi_eW1;
        const float* b1 = f ? fe_eb1 : fi_eb1;
        float a = b1[32];
        #pragma unroll
        for (int k = 0; k < 3; ++k) a += s_ei[k][e] * W1[k * F_Q + 32];
        s_hid[f][e][F_DIM + 32] = f2bf(silu_f(a));
    }
    __syncthreads();

    // ---- P2: layer-2 MFMA + fused alpha epilogue -> galpha (global)
    const int wv = tid >> 6, l = tid & 63;
    const int f = wv & 1, m0 = (wv >> 1) * 16;
    const int l15 = l & 15, g4 = l >> 4;

    bf16x8 afr[6];
    {
        const unsigned short* hrow = &s_hid[f][m0 + l15][0];
        #pragma unroll
        for (int kc = 0; kc < 6; ++kc)
            afr[kc] = *(const bf16x8*)&hrow[kc * 32 + g4 * 8];
    }
    const unsigned short* Bf = Bfrag + (size_t)f * 54 * 512 + (size_t)l * 8;

    int rcvr[4], sndr[4];
    #pragma unroll
    for (int r = 0; r < 4; ++r) {
        int e = m0 + g4 * 4 + r;
        rcvr[r] = s_rcv[e]; sndr[r] = s_snd[e];
    }

    auto run = [&](auto FC) {
        constexpr int F_ = decltype(FC)::value;
        constexpr int NH = F_ ? 3 : 4;
        constexpr int DD = F_ ? 44 : 33;
        const float* qp = F_ ? q_ev : q_inv;
        const float* kp = F_ ? k_ev : k_inv;
        float part[NH][4];
        #pragma unroll
        for (int h = 0; h < NH; ++h)
            #pragma unroll
            for (int r = 0; r < 4; ++r) part[h][r] = 0.f;

        #pragma unroll
        for (int nt = 0; nt < 9; ++nt) {
            f32x4 acc = {0.f, 0.f, 0.f, 0.f};
            #pragma unroll
            for (int kc = 0; kc < 6; ++kc) {
                bf16x8 bfr = *(const bf16x8*)(Bf + (size_t)(kc * 9 + nt) * 512);
                acc = __builtin_amdgcn_mfma_f32_16x16x32_bf16(afr[kc], bfr, acc, 0, 0, 0);
            }
            const int n = nt * 16 + l15;
            const bool nvalid = (n < F_DIM);
            const float bias = biasC[F_ * 144 + n];
            int h0v = (nt * 16) / DD;
            int bsp = (h0v + 1) * DD - nt * 16;
            #pragma unroll
            for (int r = 0; r < 4; ++r) {
                float p = 0.f;
                if (nvalid) {
                    float fw = acc[r] + bias;
                    float qv = qp[(size_t)rcvr[r] * F_DIM + n];
                    float kv = kp[(size_t)sndr[r] * F_DIM + n];
                    p = qv * kv * fw;
                }
                if (bsp >= 16) {
                    part[h0v][r] += p;
                } else {
                    float plo = (l15 < bsp) ? p : 0.f;
                    part[h0v][r] += plo;
                    if (h0v + 1 < NH) part[h0v + 1][r] += (p - plo);
                }
            }
        }
        #pragma unroll
        for (int h = 0; h < NH; ++h) {
            #pragma unroll
            for (int r = 0; r < 4; ++r) {
                float v = part[h][r];
                v += __shfl_xor(v, 1);
                v += __shfl_xor(v, 2);
                v += __shfl_xor(v, 4);
                v += __shfl_xor(v, 8);
                if (l15 == 0) {
                    int e = m0 + g4 * 4 + r;
                    galpha[(size_t)(e0g + e) * 8 + (F_ ? 4 + h : h)] =
                        v * s_c[e] * (F_ ? RCP_NORM_EV : RCP_NORM_INV);
                }
            }
        }
    };
    if (f == 0) run(std::integral_constant<int, 0>{});
    else        run(std::integral_constant<int, 1>{});
}

// ---------------------------------------------------------------------------
// K_b: node-centric aggregation. 4 nodes/block, 1 wave/node. No atomics.
// ---------------------------------------------------------------------------
__global__ __launch_bounds__(256) void gather_kernel(
    const float* __restrict__ v_inv, const float* __restrict__ sh_vec,
    const float* __restrict__ galpha,
    const int* __restrict__ gsnd, const int* __restrict__ perm,
    const int* __restrict__ off,
    float* __restrict__ a_inv, float* __restrict__ a_ev)
{
    int n = blockIdx.x * 4 + (threadIdx.x >> 6);
    int l = threadIdx.x & 63;
    int beg = off[n], end = off[n + 1];
    int c0 = l, c1 = l + 64, c2 = l + 128;   // c2 valid only for l<4
    int h0 = c0 / 33, h1 = c1 / 33;          // c2's head is always 3
    float acc0 = 0.f, acc1 = 0.f, acc2 = 0.f, aev = 0.f;
    int seg = (l < 3) ? 0 : (l < 8) ? 1 : 2;
    for (int p = beg; p < end; ++p) {
        int snd = gsnd[p];
        const float* ga = &galpha[(size_t)p * 8];
        const float* vr = &v_inv[(size_t)snd * F_DIM];
        acc0 += ga[h0] * vr[c0];
        acc1 += ga[h1] * vr[c1];
        if (l < 4) acc2 += ga[3] * vr[c2];
        if (l < EV_DIM) {
            int eid = perm[p];
            aev += ga[4 + seg] * sh_vec[(size_t)eid * EV_DIM + l];
        }
    }
    float* dr = &a_inv[(size_t)n * F_DIM];
    dr[c0] = acc0; dr[c1] = acc1;
    if (l < 4) dr[c2] = acc2;
    if (l < EV_DIM) a_ev[(size_t)n * EV_DIM + l] = aev;
}

// ---------------------------------------------------------------------------
// Kernel 3: epilogue — residuals, 135x135 interaction, outputs
// ---------------------------------------------------------------------------
__global__ __launch_bounds__(192) void epilogue_kernel(
    const float* __restrict__ inv_feat, const float* __restrict__ ev_feat,
    const float* __restrict__ acc_inv, const float* __restrict__ acc_ev,
    const float* __restrict__ W_int, const float* __restrict__ b_int,
    float* __restrict__ out0, float* __restrict__ out1)
{
    const int NB = 8;
    __shared__ float s_in[NB][INT_DIM + 1];
    __shared__ float s_ev1[NB][EV_DIM + 1];
    __shared__ float s_b[NB][3];
    int n0 = blockIdx.x * NB;
    int tid = threadIdx.x;
    for (int i = tid; i < NB * F_DIM; i += 192) {
        int nb = i / F_DIM, j = i - nb * F_DIM;
        size_t idx = (size_t)(n0 + nb) * F_DIM + j;
        s_in[nb][j] = inv_feat[idx] + acc_inv[idx];
    }
    for (int i = tid; i < NB * EV_DIM; i += 192) {
        int nb = i / EV_DIM, j = i - nb * EV_DIM;
        size_t idx = (size_t)(n0 + nb) * EV_DIM + j;
        s_ev1[nb][j] = ev_feat[idx] + acc_ev[idx];
    }
    __syncthreads();
    if (tid < NB * 3) {
        int nb = tid / 3, k = tid - nb * 3;
        int i0 = (k == 0) ? 0 : (k == 1) ? 3 : 8;
        int i1 = (k == 0) ? 3 : (k == 1) ? 8 : 15;
        float s = 0.f;
        for (int i = i0; i < i1; ++i) { float v = s_ev1[nb][i]; s += v * v; }
        s_in[nb][F_DIM + k] = s;
    }
    __syncthreads();
    if (tid < INT_DIM) {
        int j = tid;
        float b = b_int[j];
        float acc[NB];
        #pragma unroll
        for (int nb = 0; nb < NB; ++nb) acc[nb] = b;
        for (int i = 0; i < INT_DIM; ++i) {
            float w = W_int[i * INT_DIM + j];
            #pragma unroll
            for (int nb = 0; nb < NB; ++nb) acc[nb] += s_in[nb][i] * w;
        }
        if (j < F_DIM) {
            #pragma unroll
            for (int nb = 0; nb < NB; ++nb)
                out0[(size_t)(n0 + nb) * F_DIM + j] = s_in[nb][j] + acc[nb];
        } else {
            #pragma unroll
            for (int nb = 0; nb < NB; ++nb)
                s_b[nb][j - F_DIM] = acc[nb];
        }
    }
    __syncthreads();
    for (int i = tid; i < NB * EV_DIM; i += 192) {
        int nb = i / EV_DIM, ii = i - nb * EV_DIM;
        int seg = (ii < 3) ? 0 : (ii < 8) ? 1 : 2;
        out1[(size_t)(n0 + nb) * EV_DIM + ii] = s_ev1[nb][ii] * (1.f + s_b[nb][seg]);
    }
}

// ---------------------------------------------------------------------------
extern "C" void kernel_launch(void* const* d_in, const int* in_sizes, int n_in,
                              void* d_out, int out_size, void* d_ws, size_t ws_size,
                              hipStream_t stream)
{
    const float* inv_feat  = (const float*)d_in[0];
    const float* ev_feat   = (const float*)d_in[1];
    const float* rbf       = (const float*)d_in[2];
    const float* sh_vec    = (const float*)d_in[3];
    const float* cutoffs   = (const float*)d_in[4];
    const int*   senders   = (const int*)d_in[5];
    const int*   receivers = (const int*)d_in[6];
    const float* Wq_inv = (const float*)d_in[7];
    const float* Wk_inv = (const float*)d_in[8];
    const float* Wv_inv = (const float*)d_in[9];
    const float* Wq_ev  = (const float*)d_in[10];
    const float* Wk_ev  = (const float*)d_in[11];
    const float* fi_rW1 = (const float*)d_in[12];
    const float* fi_rb1 = (const float*)d_in[13];
    const float* fi_rW2 = (const float*)d_in[14];
    const float* fi_rb2 = (const float*)d_in[15];
    const float* fi_eW1 = (const float*)d_in[16];
    const float* fi_eb1 = (const float*)d_in[17];
    const float* fi_eW2 = (const float*)d_in[18];
    const float* fi_eb2 = (const float*)d_in[19];
    const float* fe_rW1 = (const float*)d_in[20];
    const float* fe_rb1 = (const float*)d_in[21];
    const float* fe_rW2 = (const float*)d_in[22];
    const float* fe_rb2 = (const float*)d_in[23];
    const float* fe_eW1 = (const float*)d_in[24];
    const float* fe_eb1 = (const float*)d_in[25];
    const float* fe_eW2 = (const float*)d_in[26];
    const float* fe_eb2 = (const float*)d_in[27];
    const float* W_int  = (const float*)d_in[28];
    const float* b_int  = (const float*)d_in[29];

    const size_t NF = (size_t)N_NODES * F_DIM;   // 6.6M floats
    float* ws    = (float*)d_ws;
    float* q_inv = ws;
    float* k_inv = ws + 1 * NF;
    float* v_inv = ws + 2 * NF;
    float* q_ev  = ws + 3 * NF;
    float* k_ev  = ws + 4 * NF;
    // aux region after the 5 projection arrays:
    float* galpha = ws + 5 * NF;                       // 400k * 8 floats
    int*   perm   = (int*)(galpha + (size_t)N_EDGES * 8);
    int*   gsnd   = perm + N_EDGES;
    int*   cnt    = gsnd + N_EDGES;                    // 50k
    int*   off    = cnt + N_NODES;                     // 50004 (padded for 16B align)
    int*   cursor = off + (N_NODES + 4);
    unsigned short* Bfrag = (unsigned short*)(cursor + N_NODES);
    float* biasC = (float*)(Bfrag + 55296);
    // aliases: q_inv/k_inv are dead after edge_alpha_kernel
    float* a_inv = q_inv;
    float* a_ev  = k_inv;

    float* out0 = (float*)d_out;
    float* out1 = out0 + NF;

    // CSR build
    hipMemsetAsync(cnt, 0, N_NODES * sizeof(int), stream);
    hist_kernel<<<(N_EDGES + 255) / 256, 256, 0, stream>>>(receivers, cnt);
    scan_kernel<<<1, 1024, 0, stream>>>(cnt, off, cursor);
    scatter_kernel<<<(N_EDGES + 255) / 256, 256, 0, stream>>>(receivers, cursor, perm);

    prep_kernel<<<27, 256, 0, stream>>>(
        fi_rW2, fi_eW2, fe_rW2, fe_eW2,
        fi_rb2, fi_eb2, fe_rb2, fe_eb2, Bfrag, biasC);

    node_proj_kernel<<<N_NODES / 8, 512, 0, stream>>>(
        inv_feat, Wq_inv, Wk_inv, Wv_inv, Wq_ev, Wk_ev,
        q_inv, k_inv, v_inv, q_ev, k_ev);

    edge_alpha_kernel<<<N_EDGES / TE, 256, 0, stream>>>(
        ev_feat, rbf, cutoffs, senders, receivers, perm,
        fi_rW1, fi_rb1, fi_eW1, fi_eb1,
        fe_rW1, fe_rb1, fe_eW1, fe_eb1,
        Bfrag, biasC,
        q_inv, k_inv, q_ev, k_ev,
        galpha, gsnd);

    gather_kernel<<<N_NODES / 4, 256, 0, stream>>>(
        v_inv, sh_vec, galpha, gsnd, perm, off, a_inv, a_ev);

    epilogue_kernel<<<N_NODES / 8, 192, 0, stream>>>(
        inv_feat, ev_feat, a_inv, a_ev, W_int, b_int, out0, out1);
}

// Round 5
// 1213.177 us; speedup vs baseline: 1.4786x; 1.2355x over previous
//
#include <hip/hip_runtime.h>
#include <type_traits>

#define N_NODES 50000
#define N_EDGES 400000
#define R_DIM   32
#define F_DIM   132
#define EV_DIM  15
#define F_Q     33
#define INT_DIM 135
#define TE      32      // edges per block in K_a

#define RCP_NORM_INV 0.17407765595569785f  // 1/sqrt(33)
#define RCP_NORM_EV  0.15075567228888181f  // 1/sqrt(44)

typedef __attribute__((ext_vector_type(8))) short bf16x8;
typedef __attribute__((ext_vector_type(4))) float f32x4;

__device__ __forceinline__ float silu_f(float x) { return x / (1.f + __expf(-x)); }

__device__ __forceinline__ unsigned short f2bf(float x) {
    union { float f; unsigned u; } c; c.f = x;
    unsigned r = c.u + 0x7FFFu + ((c.u >> 16) & 1u);  // RNE
    return (unsigned short)(r >> 16);
}

// ---------------------------------------------------------------------------
// prep_w2: layer-2 weights -> MFMA b-frag order (bf16), K=192 combined.
// ---------------------------------------------------------------------------
__global__ __launch_bounds__(256) void prep_w2_kernel(
    const float* __restrict__ fi_rW2, const float* __restrict__ fi_eW2,
    const float* __restrict__ fe_rW2, const float* __restrict__ fe_eW2,
    const float* __restrict__ fi_rb2, const float* __restrict__ fi_eb2,
    const float* __restrict__ fe_rb2, const float* __restrict__ fe_eb2,
    unsigned short* __restrict__ Bfrag, float* __restrict__ biasC)
{
    int t = blockIdx.x * 256 + threadIdx.x;
    if (t < 6912) {
        int l = t & 63, idx = t >> 6;
        int nt = idx % 9, kc = (idx / 9) % 6, f = idx / 54;
        const float* rW2 = f ? fe_rW2 : fi_rW2;
        const float* eW2 = f ? fe_eW2 : fi_eW2;
        int n = nt * 16 + (l & 15);
        unsigned short v[8];
        #pragma unroll
        for (int j = 0; j < 8; ++j) {
            int k = kc * 32 + (l >> 4) * 8 + j;
            float w = 0.f;
            if (n < F_DIM) {
                if (k < F_DIM) w = rW2[k * F_DIM + n];
                else if (k < F_DIM + F_Q) w = eW2[(k - F_DIM) * F_DIM + n];
            }
            v[j] = f2bf(w);
        }
        *(uint4*)&Bfrag[(size_t)t * 8] = *(const uint4*)v;
    }
    if (blockIdx.x == 0) {
        for (int i = threadIdx.x; i < 288; i += 256) {
            int f = i / 144, n = i % 144;
            const float* rb2 = f ? fe_rb2 : fi_rb2;
            const float* eb2 = f ? fe_eb2 : fi_eb2;
            biasC[i] = (n < F_DIM) ? (rb2[n] + eb2[n]) : 0.f;
        }
    }
}

// ---------------------------------------------------------------------------
// prep_aux: layer-1 b-frags (K=32, N=192), biasB1, node-proj weight transposes
// ---------------------------------------------------------------------------
__global__ __launch_bounds__(256) void prep_aux_kernel(
    const float* __restrict__ fi_rW1, const float* __restrict__ fe_rW1,
    const float* __restrict__ fi_rb1, const float* __restrict__ fi_eb1,
    const float* __restrict__ fe_rb1, const float* __restrict__ fe_eb1,
    const float* __restrict__ Wq_inv, const float* __restrict__ Wk_inv,
    const float* __restrict__ Wv_inv,
    const float* __restrict__ Wq_ev, const float* __restrict__ Wk_ev,
    unsigned short* __restrict__ B1frag, float* __restrict__ biasB1,
    float* __restrict__ WtQi, float* __restrict__ WtKi, float* __restrict__ WtVi,
    float* __restrict__ WtQe, float* __restrict__ WtKe)
{
    int t = blockIdx.x * 256 + threadIdx.x;
    if (t < 1536) {
        // B1frag[f][nt<12][lane][8]; value = rW1[k][n] (n<132) else 0; k=(l>>4)*8+j
        int l = t & 63, idx = t >> 6;     // idx = f*12 + nt
        int nt = idx % 12, f = idx / 12;
        const float* rW1 = f ? fe_rW1 : fi_rW1;
        int n = nt * 16 + (l & 15);
        unsigned short v[8];
        #pragma unroll
        for (int j = 0; j < 8; ++j) {
            int k = (l >> 4) * 8 + j;
            float w = (n < F_DIM) ? rW1[k * F_DIM + n] : 0.f;
            v[j] = f2bf(w);
        }
        *(uint4*)&B1frag[(size_t)t * 8] = *(const uint4*)v;
    } else if (t < 1920) {
        int i = t - 1536;                 // biasB1[f][192]
        int f = i / 192, n = i % 192;
        const float* rb1 = f ? fe_rb1 : fi_rb1;
        const float* eb1 = f ? fe_eb1 : fi_eb1;
        biasB1[i] = (n < F_DIM) ? rb1[n] : ((n < 165) ? eb1[n - F_DIM] : 0.f);
    } else if (t < 1920 + 14256) {
        int i = t - 1920;                 // Wt_inv[arr][(h*33+e)*36 + d]
        int arr = i / 4752, r = i % 4752;
        int h = r / 1188, r2 = r % 1188;
        int e = r2 / 36, d = r2 % 36;
        const float* src = (arr == 0) ? Wq_inv : (arr == 1) ? Wk_inv : Wv_inv;
        float* dst = (arr == 0) ? WtQi : (arr == 1) ? WtKi : WtVi;
        dst[r] = (d < 33) ? src[h * 1089 + d * 33 + e] : 0.f;
    } else if (t < 16176 + 12672) {
        int i = t - 16176;                // Wt_ev[arr][(h*44+e)*48 + d]
        int arr = i / 6336, r = i % 6336;
        int h = r / 2112, r2 = r % 2112;
        int e = r2 / 48, d = r2 % 48;
        const float* src = arr ? Wk_ev : Wq_ev;
        float* dst = arr ? WtKe : WtQe;
        dst[r] = (d < 44) ? src[h * 1936 + d * 44 + e] : 0.f;
    }
}

// ---------------------------------------------------------------------------
// CSR build: histogram -> single-block scan -> scatter permutation
// ---------------------------------------------------------------------------
__global__ __launch_bounds__(256) void hist_kernel(
    const int* __restrict__ receivers, int* __restrict__ cnt)
{
    int i = blockIdx.x * 256 + threadIdx.x;
    if (i < N_EDGES) atomicAdd(&cnt[receivers[i]], 1);
}

__global__ __launch_bounds__(1024) void scan_kernel(
    const int* __restrict__ cnt, int* __restrict__ off, int* __restrict__ cursor)
{
    __shared__ int sums[1024];
    const int CHUNK = 49;
    int t = threadIdx.x;
    int base = t * CHUNK;
    int s = 0;
    for (int i = 0; i < CHUNK; ++i) {
        int idx = base + i;
        if (idx < N_NODES) s += cnt[idx];
    }
    sums[t] = s;
    __syncthreads();
    for (int d = 1; d < 1024; d <<= 1) {
        int v = (t >= d) ? sums[t - d] : 0;
        __syncthreads();
        sums[t] += v;
        __syncthreads();
    }
    int run = (t == 0) ? 0 : sums[t - 1];
    for (int i = 0; i < CHUNK; ++i) {
        int idx = base + i;
        if (idx < N_NODES) {
            off[idx] = run; cursor[idx] = run;
            run += cnt[idx];
        }
    }
    if (t == 0) off[N_NODES] = N_EDGES;
}

__global__ __launch_bounds__(256) void scatter_kernel(
    const int* __restrict__ receivers, int* __restrict__ cursor,
    int* __restrict__ perm)
{
    int i = blockIdx.x * 256 + threadIdx.x;
    if (i < N_EDGES) {
        int pos = atomicAdd(&cursor[receivers[i]], 1);
        perm[pos] = i;
    }
}

// ---------------------------------------------------------------------------
// Kernel 1: node projections with transposed weights (contiguous K, float4)
// ---------------------------------------------------------------------------
__global__ __launch_bounds__(512) void node_proj_kernel(
    const float* __restrict__ x,
    const float* __restrict__ WtQi, const float* __restrict__ WtKi,
    const float* __restrict__ WtVi,
    const float* __restrict__ WtQe, const float* __restrict__ WtKe,
    float* __restrict__ q_inv, float* __restrict__ k_inv, float* __restrict__ v_inv,
    float* __restrict__ q_ev, float* __restrict__ k_ev)
{
    __shared__ float xs_i[8][144];   // per-head padded to 36
    __shared__ float xs_e[8][144];   // per-head padded to 48
    int node0 = blockIdx.x * 8;
    for (int i = threadIdx.x; i < 8 * 144; i += 512) {
        int nb = i / 144, t = i % 144;
        int h = t / 36, d = t % 36;
        xs_i[nb][t] = (d < 33) ? x[(size_t)(node0 + nb) * F_DIM + h * 33 + d] : 0.f;
    }
    for (int i = threadIdx.x; i < 8 * 144; i += 512) {
        int nb = i / 144, t = i % 144;
        int h = t / 48, d = t % 48;
        xs_e[nb][t] = (d < 44) ? x[(size_t)(node0 + nb) * F_DIM + h * 44 + d] : 0.f;
    }
    __syncthreads();
    int nb = threadIdx.x >> 6;
    int lane = threadIdx.x & 63;
    int n = node0 + nb;
    for (int o = lane; o < 5 * F_DIM; o += 64) {
        int arr = o / F_DIM, ch = o - arr * F_DIM;
        float acc = 0.f;
        if (arr < 3) {
            int h = ch / 33, e = ch - h * 33;
            const float* W = ((arr == 0) ? WtQi : (arr == 1) ? WtKi : WtVi)
                             + (h * 33 + e) * 36;
            const float* xr = &xs_i[nb][h * 36];
            #pragma unroll
            for (int d4 = 0; d4 < 9; ++d4) {
                float4 w = *(const float4*)&W[d4 * 4];
                float4 xv = *(const float4*)&xr[d4 * 4];
                acc += w.x * xv.x + w.y * xv.y + w.z * xv.z + w.w * xv.w;
            }
            if (arr < 2) acc = silu_f(acc);
            ((arr == 0) ? q_inv : (arr == 1) ? k_inv : v_inv)[(size_t)n * F_DIM + ch] = acc;
        } else {
            int h = ch / 44, e = ch - h * 44;
            const float* W = ((arr == 3) ? WtQe : WtKe) + (h * 44 + e) * 48;
            const float* xr = &xs_e[nb][h * 48];
            #pragma unroll
            for (int d4 = 0; d4 < 12; ++d4) {
                float4 w = *(const float4*)&W[d4 * 4];
                float4 xv = *(const float4*)&xr[d4 * 4];
                acc += w.x * xv.x + w.y * xv.y + w.z * xv.z + w.w * xv.w;
            }
            acc = silu_f(acc);
            ((arr == 3) ? q_ev : k_ev)[(size_t)n * F_DIM + ch] = acc;
        }
    }
}

// ---------------------------------------------------------------------------
// K_a: edge filters — BOTH layers MFMA — + alpha. No fp atomics.
// 256 thr = 4 waves; wave = (filter f, M-tile of 16 edges).
// ---------------------------------------------------------------------------
__global__ __launch_bounds__(256) void edge_alpha_kernel(
    const float* __restrict__ ev_feat, const float* __restrict__ rbf,
    const float* __restrict__ cutoffs,
    const int* __restrict__ senders, const int* __restrict__ receivers,
    const int* __restrict__ perm,
    const float* __restrict__ fi_eW1, const float* __restrict__ fe_eW1,
    const unsigned short* __restrict__ B1frag, const float* __restrict__ biasB1,
    const unsigned short* __restrict__ Bfrag, const float* __restrict__ biasC,
    const float* __restrict__ q_inv, const float* __restrict__ k_inv,
    const float* __restrict__ q_ev, const float* __restrict__ k_ev,
    float* __restrict__ galpha, int* __restrict__ gsnd)
{
    // s_hid rows: [filter][edge][200 bf16]; cols 0..164 real, 165..191 exact 0
    __shared__ __align__(16) unsigned short s_hid[2][TE][200];
    __shared__ __align__(16) unsigned short s_ain[TE][40];  // bf16 rbf rows (pad 40)
    __shared__ float s_d2[TE][16];
    __shared__ float s_ei[3][TE];
    __shared__ float s_c[TE];
    __shared__ int s_snd[TE], s_rcv[TE], s_eid[TE];

    const int e0g = blockIdx.x * TE;
    const int tid = threadIdx.x;

    // ---- P0a: edge meta via CSR perm
    if (tid < TE) {
        int eid = perm[e0g + tid];
        s_eid[tid] = eid;
        int sn = senders[eid], rc = receivers[eid];
        s_snd[tid] = sn; s_rcv[tid] = rc;
        s_c[tid] = cutoffs[eid];
        gsnd[e0g + tid] = sn;
    }
    __syncthreads();
    // ---- P0b: rbf -> bf16 LDS rows; ev_diff^2
    for (int i = tid; i < TE * R_DIM; i += 256) {
        int e = i >> 5, k = i & 31;
        s_ain[e][k] = f2bf(rbf[(size_t)s_eid[e] * R_DIM + k]);
    }
    for (int i = tid; i < TE * EV_DIM; i += 256) {
        int e = i / EV_DIM, j = i - e * EV_DIM;
        float d = ev_feat[(size_t)s_snd[e] * EV_DIM + j]
                - ev_feat[(size_t)s_rcv[e] * EV_DIM + j];
        s_d2[e][j] = d * d;
    }
    __syncthreads();
    if (tid < TE * 3) {
        int e = tid / 3, k2 = tid - e * 3;
        int i0 = (k2 == 0) ? 0 : (k2 == 1) ? 3 : 8;
        int i1 = (k2 == 0) ? 3 : (k2 == 1) ? 8 : 15;
        float s = 0.f;
        for (int i = i0; i < i1; ++i) s += s_d2[e][i];
        s_ei[k2][e] = s;
    }
    __syncthreads();

    const int wv = tid >> 6, l = tid & 63;
    const int f = wv & 1, m0 = (wv >> 1) * 16;
    const int l15 = l & 15, g4 = l >> 4;

    // ---- P1: layer 1 via MFMA (K=32), per-wave; ev-branch as rank-3 epilogue.
    // Wave writes only its own (f, mtile) rows -> no barrier before P2.
    {
        bf16x8 a1 = *(const bf16x8*)&s_ain[m0 + l15][g4 * 8];
        const unsigned short* B1f = B1frag + (size_t)f * 6144 + (size_t)l * 8;
        const float* eW1f = f ? fe_eW1 : fi_eW1;
        #pragma unroll
        for (int nt = 0; nt < 12; ++nt) {
            f32x4 c = {0.f, 0.f, 0.f, 0.f};
            bf16x8 b1 = *(const bf16x8*)(B1f + (size_t)nt * 512);
            c = __builtin_amdgcn_mfma_f32_16x16x32_bf16(a1, b1, c, 0, 0, 0);
            const int n = nt * 16 + l15;
            const float bias = biasB1[f * 192 + n];
            float w0 = 0.f, w1 = 0.f, w2 = 0.f;
            if (n >= F_DIM && n < 165) {
                w0 = eW1f[n - F_DIM];
                w1 = eW1f[F_Q + n - F_DIM];
                w2 = eW1f[2 * F_Q + n - F_DIM];
            }
            #pragma unroll
            for (int r = 0; r < 4; ++r) {
                int e = m0 + g4 * 4 + r;
                float eic = w0 * s_ei[0][e] + w1 * s_ei[1][e] + w2 * s_ei[2][e];
                float v = silu_f(c[r] + bias + eic);   // exact 0 for n>=165
                s_hid[f][e][n] = f2bf(v);
            }
        }
    }

    // ---- P2: layer-2 MFMA (K=192) + fused alpha epilogue -> galpha
    bf16x8 afr[6];
    {
        const unsigned short* hrow = &s_hid[f][m0 + l15][0];
        #pragma unroll
        for (int kc = 0; kc < 6; ++kc)
            afr[kc] = *(const bf16x8*)&hrow[kc * 32 + g4 * 8];
    }
    const unsigned short* Bf = Bfrag + (size_t)f * 54 * 512 + (size_t)l * 8;

    int rcvr[4], sndr[4];
    #pragma unroll
    for (int r = 0; r < 4; ++r) {
        int e = m0 + g4 * 4 + r;
        rcvr[r] = s_rcv[e]; sndr[r] = s_snd[e];
    }

    auto run = [&](auto FC) {
        constexpr int F_ = decltype(FC)::value;
        constexpr int NH = F_ ? 3 : 4;
        constexpr int DD = F_ ? 44 : 33;
        const float* qp = F_ ? q_ev : q_inv;
        const float* kp = F_ ? k_ev : k_inv;
        float part[NH][4];
        #pragma unroll
        for (int h = 0; h < NH; ++h)
            #pragma unroll
            for (int r = 0; r < 4; ++r) part[h][r] = 0.f;

        #pragma unroll
        for (int nt = 0; nt < 9; ++nt) {
            f32x4 acc = {0.f, 0.f, 0.f, 0.f};
            #pragma unroll
            for (int kc = 0; kc < 6; ++kc) {
                bf16x8 bfr = *(const bf16x8*)(Bf + (size_t)(kc * 9 + nt) * 512);
                acc = __builtin_amdgcn_mfma_f32_16x16x32_bf16(afr[kc], bfr, acc, 0, 0, 0);
            }
            const int n = nt * 16 + l15;
            const bool nvalid = (n < F_DIM);
            const float bias = biasC[F_ * 144 + n];
            int h0v = (nt * 16) / DD;
            int bsp = (h0v + 1) * DD - nt * 16;
            #pragma unroll
            for (int r = 0; r < 4; ++r) {
                float p = 0.f;
                if (nvalid) {
                    float fw = acc[r] + bias;
                    float qv = qp[(size_t)rcvr[r] * F_DIM + n];
                    float kv = kp[(size_t)sndr[r] * F_DIM + n];
                    p = qv * kv * fw;
                }
                if (bsp >= 16) {
                    part[h0v][r] += p;
                } else {
                    float plo = (l15 < bsp) ? p : 0.f;
                    part[h0v][r] += plo;
                    if (h0v + 1 < NH) part[h0v + 1][r] += (p - plo);
                }
            }
        }
        #pragma unroll
        for (int h = 0; h < NH; ++h) {
            #pragma unroll
            for (int r = 0; r < 4; ++r) {
                float v = part[h][r];
                v += __shfl_xor(v, 1);
                v += __shfl_xor(v, 2);
                v += __shfl_xor(v, 4);
                v += __shfl_xor(v, 8);
                if (l15 == 0) {
                    int e = m0 + g4 * 4 + r;
                    galpha[(size_t)(e0g + e) * 8 + (F_ ? 4 + h : h)] =
                        v * s_c[e] * (F_ ? RCP_NORM_EV : RCP_NORM_INV);
                }
            }
        }
    };
    if (f == 0) run(std::integral_constant<int, 0>{});
    else        run(std::integral_constant<int, 1>{});
}

// ---------------------------------------------------------------------------
// K_b: node-centric aggregation. 4 nodes/block, 1 wave/node. No atomics.
// ---------------------------------------------------------------------------
__global__ __launch_bounds__(256) void gather_kernel(
    const float* __restrict__ v_inv, const float* __restrict__ sh_vec,
    const float* __restrict__ galpha,
    const int* __restrict__ gsnd, const int* __restrict__ perm,
    const int* __restrict__ off,
    float* __restrict__ a_inv, float* __restrict__ a_ev)
{
    int n = blockIdx.x * 4 + (threadIdx.x >> 6);
    int l = threadIdx.x & 63;
    int beg = off[n], end = off[n + 1];
    int c0 = l, c1 = l + 64, c2 = l + 128;
    int h0 = c0 / 33, h1 = c1 / 33;
    float acc0 = 0.f, acc1 = 0.f, acc2 = 0.f, aev = 0.f;
    int seg = (l < 3) ? 0 : (l < 8) ? 1 : 2;
    for (int p = beg; p < end; ++p) {
        int snd = gsnd[p];
        const float* ga = &galpha[(size_t)p * 8];
        const float* vr = &v_inv[(size_t)snd * F_DIM];
        acc0 += ga[h0] * vr[c0];
        acc1 += ga[h1] * vr[c1];
        if (l < 4) acc2 += ga[3] * vr[c2];
        if (l < EV_DIM) {
            int eid = perm[p];
            aev += ga[4 + seg] * sh_vec[(size_t)eid * EV_DIM + l];
        }
    }
    float* dr = &a_inv[(size_t)n * F_DIM];
    dr[c0] = acc0; dr[c1] = acc1;
    if (l < 4) dr[c2] = acc2;
    if (l < EV_DIM) a_ev[(size_t)n * EV_DIM + l] = aev;
}

// ---------------------------------------------------------------------------
// Kernel 3: epilogue — residuals, 135x135 interaction, outputs. 16 nodes/block.
// ---------------------------------------------------------------------------
__global__ __launch_bounds__(256) void epilogue_kernel(
    const float* __restrict__ inv_feat, const float* __restrict__ ev_feat,
    const float* __restrict__ acc_inv, const float* __restrict__ acc_ev,
    const float* __restrict__ W_int, const float* __restrict__ b_int,
    float* __restrict__ out0, float* __restrict__ out1)
{
    const int NB = 16;
    __shared__ float s_in[NB][INT_DIM + 1];
    __shared__ float s_ev1[NB][EV_DIM + 1];
    __shared__ float s_b[NB][3];
    int n0 = blockIdx.x * NB;
    int tid = threadIdx.x;
    for (int i = tid; i < NB * F_DIM; i += 256) {
        int nb = i / F_DIM, j = i - nb * F_DIM;
        size_t idx = (size_t)(n0 + nb) * F_DIM + j;
        s_in[nb][j] = inv_feat[idx] + acc_inv[idx];
    }
    for (int i = tid; i < NB * EV_DIM; i += 256) {
        int nb = i / EV_DIM, j = i - nb * EV_DIM;
        size_t idx = (size_t)(n0 + nb) * EV_DIM + j;
        s_ev1[nb][j] = ev_feat[idx] + acc_ev[idx];
    }
    __syncthreads();
    if (tid < NB * 3) {
        int nb = tid / 3, k = tid - nb * 3;
        int i0 = (k == 0) ? 0 : (k == 1) ? 3 : 8;
        int i1 = (k == 0) ? 3 : (k == 1) ? 8 : 15;
        float s = 0.f;
        for (int i = i0; i < i1; ++i) { float v = s_ev1[nb][i]; s += v * v; }
        s_in[nb][F_DIM + k] = s;
    }
    __syncthreads();
    if (tid < INT_DIM) {
        int j = tid;
        float b = b_int[j];
        float acc[NB];
        #pragma unroll
        for (int nb = 0; nb < NB; ++nb) acc[nb] = b;
        for (int i = 0; i < INT_DIM; ++i) {
            float w = W_int[i * INT_DIM + j];
            #pragma unroll
            for (int nb = 0; nb < NB; ++nb) acc[nb] += s_in[nb][i] * w;
        }
        if (j < F_DIM) {
            #pragma unroll
            for (int nb = 0; nb < NB; ++nb)
                out0[(size_t)(n0 + nb) * F_DIM + j] = s_in[nb][j] + acc[nb];
        } else {
            #pragma unroll
            for (int nb = 0; nb < NB; ++nb)
                s_b[nb][j - F_DIM] = acc[nb];
        }
    }
    __syncthreads();
    for (int i = tid; i < NB * EV_DIM; i += 256) {
        int nb = i / EV_DIM, ii = i - nb * EV_DIM;
        int seg = (ii < 3) ? 0 : (ii < 8) ? 1 : 2;
        out1[(size_t)(n0 + nb) * EV_DIM + ii] = s_ev1[nb][ii] * (1.f + s_b[nb][seg]);
    }
}

// ---------------------------------------------------------------------------
extern "C" void kernel_launch(void* const* d_in, const int* in_sizes, int n_in,
                              void* d_out, int out_size, void* d_ws, size_t ws_size,
                              hipStream_t stream)
{
    const float* inv_feat  = (const float*)d_in[0];
    const float* ev_feat   = (const float*)d_in[1];
    const float* rbf       = (const float*)d_in[2];
    const float* sh_vec    = (const float*)d_in[3];
    const float* cutoffs   = (const float*)d_in[4];
    const int*   senders   = (const int*)d_in[5];
    const int*   receivers = (const int*)d_in[6];
    const float* Wq_inv = (const float*)d_in[7];
    const float* Wk_inv = (const float*)d_in[8];
    const float* Wv_inv = (const float*)d_in[9];
    const float* Wq_ev  = (const float*)d_in[10];
    const float* Wk_ev  = (const float*)d_in[11];
    const float* fi_rW1 = (const float*)d_in[12];
    const float* fi_rb1 = (const float*)d_in[13];
    const float* fi_rW2 = (const float*)d_in[14];
    const float* fi_rb2 = (const float*)d_in[15];
    const float* fi_eW1 = (const float*)d_in[16];
    const float* fi_eb1 = (const float*)d_in[17];
    const float* fi_eW2 = (const float*)d_in[18];
    const float* fi_eb2 = (const float*)d_in[19];
    const float* fe_rW1 = (const float*)d_in[20];
    const float* fe_rb1 = (const float*)d_in[21];
    const float* fe_rW2 = (const float*)d_in[22];
    const float* fe_rb2 = (const float*)d_in[23];
    const float* fe_eW1 = (const float*)d_in[24];
    const float* fe_eb1 = (const float*)d_in[25];
    const float* fe_eW2 = (const float*)d_in[26];
    const float* fe_eb2 = (const float*)d_in[27];
    const float* W_int  = (const float*)d_in[28];
    const float* b_int  = (const float*)d_in[29];

    const size_t NF = (size_t)N_NODES * F_DIM;
    float* ws    = (float*)d_ws;
    float* q_inv = ws;
    float* k_inv = ws + 1 * NF;
    float* v_inv = ws + 2 * NF;
    float* q_ev  = ws + 3 * NF;
    float* k_ev  = ws + 4 * NF;
    float* galpha = ws + 5 * NF;                       // 400k * 8 floats
    int*   perm   = (int*)(galpha + (size_t)N_EDGES * 8);
    int*   gsnd   = perm + N_EDGES;
    int*   cnt    = gsnd + N_EDGES;
    int*   off    = cnt + N_NODES;
    int*   cursor = off + (N_NODES + 4);
    unsigned short* Bfrag  = (unsigned short*)(cursor + N_NODES);  // 55296
    float*          biasC  = (float*)(Bfrag + 55296);              // 288
    unsigned short* B1frag = (unsigned short*)(biasC + 288);       // 12288
    float*          biasB1 = (float*)(B1frag + 12288);             // 384
    float* WtQi = biasB1 + 384;        // 4752 each
    float* WtKi = WtQi + 4752;
    float* WtVi = WtKi + 4752;
    float* WtQe = WtVi + 4752;         // 6336 each
    float* WtKe = WtQe + 6336;
    float* a_inv = q_inv;              // dead after edge_alpha
    float* a_ev  = k_inv;

    float* out0 = (float*)d_out;
    float* out1 = out0 + NF;

    hipMemsetAsync(cnt, 0, N_NODES * sizeof(int), stream);
    hist_kernel<<<(N_EDGES + 255) / 256, 256, 0, stream>>>(receivers, cnt);
    scan_kernel<<<1, 1024, 0, stream>>>(cnt, off, cursor);
    scatter_kernel<<<(N_EDGES + 255) / 256, 256, 0, stream>>>(receivers, cursor, perm);

    prep_w2_kernel<<<27, 256, 0, stream>>>(
        fi_rW2, fi_eW2, fe_rW2, fe_eW2,
        fi_rb2, fi_eb2, fe_rb2, fe_eb2, Bfrag, biasC);

    prep_aux_kernel<<<113, 256, 0, stream>>>(
        fi_rW1, fe_rW1, fi_rb1, fi_eb1, fe_rb1, fe_eb1,
        Wq_inv, Wk_inv, Wv_inv, Wq_ev, Wk_ev,
        B1frag, biasB1, WtQi, WtKi, WtVi, WtQe, WtKe);

    node_proj_kernel<<<N_NODES / 8, 512, 0, stream>>>(
        inv_feat, WtQi, WtKi, WtVi, WtQe, WtKe,
        q_inv, k_inv, v_inv, q_ev, k_ev);

    edge_alpha_kernel<<<N_EDGES / TE, 256, 0, stream>>>(
        ev_feat, rbf, cutoffs, senders, receivers, perm,
        fi_eW1, fe_eW1, B1frag, biasB1, Bfrag, biasC,
        q_inv, k_inv, q_ev, k_ev,
        galpha, gsnd);

    gather_kernel<<<N_NODES / 4, 256, 0, stream>>>(
        v_inv, sh_vec, galpha, gsnd, perm, off, a_inv, a_ev);

    epilogue_kernel<<<N_NODES / 16, 256, 0, stream>>>(
        inv_feat, ev_feat, a_inv, a_ev, W_int, b_int, out0, out1);
}

// Round 6
// 1130.717 us; speedup vs baseline: 1.5864x; 1.0729x over previous
//
#include <hip/hip_runtime.h>
#include <type_traits>

#define N_NODES 50000
#define N_EDGES 400000
#define R_DIM   32
#define F_DIM   132
#define EV_DIM  15
#define F_Q     33
#define INT_DIM 135
#define TE      32      // edges per block in K_a
#define NPB     32      // nodes per block in node_proj

#define RCP_NORM_INV 0.17407765595569785f  // 1/sqrt(33)
#define RCP_NORM_EV  0.15075567228888181f  // 1/sqrt(44)

typedef __attribute__((ext_vector_type(8))) short bf16x8;
typedef __attribute__((ext_vector_type(4))) float f32x4;

__device__ __forceinline__ float silu_f(float x) { return x / (1.f + __expf(-x)); }

__device__ __forceinline__ unsigned short f2bf(float x) {
    union { float f; unsigned u; } c; c.f = x;
    unsigned r = c.u + 0x7FFFu + ((c.u >> 16) & 1u);  // RNE
    return (unsigned short)(r >> 16);
}

// ---------------------------------------------------------------------------
// prep_w2: layer-2 weights -> MFMA b-frag order (bf16), K=192 combined.
// ---------------------------------------------------------------------------
__global__ __launch_bounds__(256) void prep_w2_kernel(
    const float* __restrict__ fi_rW2, const float* __restrict__ fi_eW2,
    const float* __restrict__ fe_rW2, const float* __restrict__ fe_eW2,
    const float* __restrict__ fi_rb2, const float* __restrict__ fi_eb2,
    const float* __restrict__ fe_rb2, const float* __restrict__ fe_eb2,
    unsigned short* __restrict__ Bfrag, float* __restrict__ biasC)
{
    int t = blockIdx.x * 256 + threadIdx.x;
    if (t < 6912) {
        int l = t & 63, idx = t >> 6;
        int nt = idx % 9, kc = (idx / 9) % 6, f = idx / 54;
        const float* rW2 = f ? fe_rW2 : fi_rW2;
        const float* eW2 = f ? fe_eW2 : fi_eW2;
        int n = nt * 16 + (l & 15);
        unsigned short v[8];
        #pragma unroll
        for (int j = 0; j < 8; ++j) {
            int k = kc * 32 + (l >> 4) * 8 + j;
            float w = 0.f;
            if (n < F_DIM) {
                if (k < F_DIM) w = rW2[k * F_DIM + n];
                else if (k < F_DIM + F_Q) w = eW2[(k - F_DIM) * F_DIM + n];
            }
            v[j] = f2bf(w);
        }
        *(uint4*)&Bfrag[(size_t)t * 8] = *(const uint4*)v;
    }
    if (blockIdx.x == 0) {
        for (int i = threadIdx.x; i < 288; i += 256) {
            int f = i / 144, n = i % 144;
            const float* rb2 = f ? fe_rb2 : fi_rb2;
            const float* eb2 = f ? fe_eb2 : fi_eb2;
            biasC[i] = (n < F_DIM) ? (rb2[n] + eb2[n]) : 0.f;
        }
    }
}

// ---------------------------------------------------------------------------
// prep_aux: edge layer-1 b-frags + biasB1 + node-proj b-frags (Bnp).
// Bnp blocks: Qi 0-23, Ki 24-47, Vi 48-71 (4h x 2kc x 3nt), Qe 72-89, Ke 90-107.
// ---------------------------------------------------------------------------
__global__ __launch_bounds__(256) void prep_aux_kernel(
    const float* __restrict__ fi_rW1, const float* __restrict__ fe_rW1,
    const float* __restrict__ fi_rb1, const float* __restrict__ fi_eb1,
    const float* __restrict__ fe_rb1, const float* __restrict__ fe_eb1,
    const float* __restrict__ Wq_inv, const float* __restrict__ Wk_inv,
    const float* __restrict__ Wv_inv,
    const float* __restrict__ Wq_ev, const float* __restrict__ Wk_ev,
    unsigned short* __restrict__ B1frag, float* __restrict__ biasB1,
    unsigned short* __restrict__ Bnp)
{
    int t = blockIdx.x * 256 + threadIdx.x;
    if (t < 1536) {
        int l = t & 63, idx = t >> 6;     // idx = f*12 + nt
        int nt = idx % 12, f = idx / 12;
        const float* rW1 = f ? fe_rW1 : fi_rW1;
        int n = nt * 16 + (l & 15);
        unsigned short v[8];
        #pragma unroll
        for (int j = 0; j < 8; ++j) {
            int k = (l >> 4) * 8 + j;
            float w = (n < F_DIM) ? rW1[k * F_DIM + n] : 0.f;
            v[j] = f2bf(w);
        }
        *(uint4*)&B1frag[(size_t)t * 8] = *(const uint4*)v;
    } else if (t < 1920) {
        int i = t - 1536;
        int f = i / 192, n = i % 192;
        const float* rb1 = f ? fe_rb1 : fi_rb1;
        const float* eb1 = f ? fe_eb1 : fi_eb1;
        biasB1[i] = (n < F_DIM) ? rb1[n] : ((n < 165) ? eb1[n - F_DIM] : 0.f);
    } else if (t < 1920 + 6912) {
        int u = t - 1920;
        int l = u & 63, blk = u >> 6;
        int n = 0; const float* W = nullptr; int D = 0, h = 0, kc = 0;
        if (blk < 72) {
            int arr = blk / 24, wb = blk % 24;
            h = wb / 6; kc = (wb % 6) / 3; int nt = wb % 3;
            W = (arr == 0) ? Wq_inv : (arr == 1) ? Wk_inv : Wv_inv;
            D = 33; n = nt * 16 + (l & 15);
            W += h * 1089;
        } else {
            int b2 = blk - 72;
            int which = b2 / 18, wb = b2 % 18;
            h = wb / 6; kc = (wb % 6) / 3; int nt = wb % 3;
            W = which ? Wk_ev : Wq_ev;
            D = 44; n = nt * 16 + (l & 15);
            W += h * 1936;
        }
        unsigned short v[8];
        #pragma unroll
        for (int j = 0; j < 8; ++j) {
            int k = kc * 32 + (l >> 4) * 8 + j;
            float w = (k < D && n < D) ? W[k * D + n] : 0.f;
            v[j] = f2bf(w);
        }
        *(uint4*)&Bnp[(size_t)u * 8] = *(const uint4*)v;
    }
}

// ---------------------------------------------------------------------------
// CSR build: histogram -> coalesced 3-phase scan -> scatter permutation
// ---------------------------------------------------------------------------
__global__ __launch_bounds__(256) void hist_kernel(
    const int* __restrict__ receivers, int* __restrict__ cnt)
{
    int i = blockIdx.x * 256 + threadIdx.x;
    if (i < N_EDGES) atomicAdd(&cnt[receivers[i]], 1);
}

__global__ __launch_bounds__(1024) void scan_tile_sum(
    const int* __restrict__ cnt, int* __restrict__ tsum)
{
    int idx = blockIdx.x * 1024 + threadIdx.x;
    int v = (idx < N_NODES) ? cnt[idx] : 0;
    for (int o = 32; o > 0; o >>= 1) v += __shfl_down(v, o);
    __shared__ int wsum[16];
    if ((threadIdx.x & 63) == 0) wsum[threadIdx.x >> 6] = v;
    __syncthreads();
    if (threadIdx.x == 0) {
        int s = 0;
        for (int i = 0; i < 16; ++i) s += wsum[i];
        tsum[blockIdx.x] = s;
    }
}

__global__ __launch_bounds__(64) void scan_base(
    const int* __restrict__ tsum, int* __restrict__ tbase)
{
    if (threadIdx.x == 0) {
        int run = 0;
        for (int i = 0; i < 49; ++i) { tbase[i] = run; run += tsum[i]; }
    }
}

__global__ __launch_bounds__(1024) void scan_tile(
    const int* __restrict__ cnt, const int* __restrict__ tbase,
    int* __restrict__ off, int* __restrict__ cursor)
{
    __shared__ int s[1024];
    int t = threadIdx.x;
    int idx = blockIdx.x * 1024 + t;
    int v = (idx < N_NODES) ? cnt[idx] : 0;
    s[t] = v;
    __syncthreads();
    for (int d = 1; d < 1024; d <<= 1) {
        int x = (t >= d) ? s[t - d] : 0;
        __syncthreads();
        s[t] += x;
        __syncthreads();
    }
    int o = tbase[blockIdx.x] + s[t] - v;
    if (idx < N_NODES) { off[idx] = o; cursor[idx] = o; }
    if (idx == 0) off[N_NODES] = N_EDGES;
}

__global__ __launch_bounds__(256) void scatter_kernel(
    const int* __restrict__ receivers, int* __restrict__ cursor,
    int* __restrict__ perm)
{
    int i = blockIdx.x * 256 + threadIdx.x;
    if (i < N_EDGES) {
        int pos = atomicAdd(&cursor[receivers[i]], 1);
        perm[pos] = i;
    }
}

// ---------------------------------------------------------------------------
// Kernel 1: node projections via MFMA. 32 nodes/block, 4 waves.
// wave = (m-tile of 16 nodes, half of array work).
// ---------------------------------------------------------------------------
__global__ __launch_bounds__(256) void node_proj_kernel(
    const float* __restrict__ x,
    const unsigned short* __restrict__ Bnp,
    float* __restrict__ q_inv, float* __restrict__ k_inv, float* __restrict__ v_inv,
    float* __restrict__ q_ev, float* __restrict__ k_ev)
{
    // per node: segs 0..3 = inv heads (64 k-slots each, 33 real), 4..6 = ev heads (44 real)
    __shared__ __align__(16) unsigned short sx[NPB][456];  // 456: +8 pad (bank stagger)
    const int node0 = blockIdx.x * NPB;
    const int tid = threadIdx.x;
    for (int i = tid; i < NPB * 448; i += 256) {
        int nd = i / 448, t = i % 448;
        int seg = t >> 6, d = t & 63;
        float v = 0.f;
        int gn = node0 + nd;
        if (gn < N_NODES) {
            if (seg < 4) { if (d < 33) v = x[(size_t)gn * F_DIM + seg * 33 + d]; }
            else         { int h = seg - 4; if (d < 44) v = x[(size_t)gn * F_DIM + h * 44 + d]; }
        }
        sx[nd][t] = f2bf(v);
    }
    __syncthreads();
    const int wv = tid >> 6, l = tid & 63, l15 = l & 15, g4 = l >> 4;
    const int half = wv & 1, m0 = (wv >> 1) * 16;
    const unsigned short* arow = &sx[m0 + l15][0];
    const unsigned short* Bl = Bnp + (size_t)l * 8;

    auto do_inv = [&](int arr, float* __restrict__ out, bool dosilu) {
        const unsigned short* Ba = Bl + (size_t)arr * 24 * 512;
        #pragma unroll
        for (int h = 0; h < 4; ++h) {
            bf16x8 a0 = *(const bf16x8*)&arow[h * 64 + g4 * 8];
            bf16x8 a1 = *(const bf16x8*)&arow[h * 64 + 32 + g4 * 8];
            #pragma unroll
            for (int nt = 0; nt < 3; ++nt) {
                f32x4 c = {0.f, 0.f, 0.f, 0.f};
                c = __builtin_amdgcn_mfma_f32_16x16x32_bf16(
                        a0, *(const bf16x8*)(Ba + (size_t)((h * 2 + 0) * 3 + nt) * 512), c, 0, 0, 0);
                c = __builtin_amdgcn_mfma_f32_16x16x32_bf16(
                        a1, *(const bf16x8*)(Ba + (size_t)((h * 2 + 1) * 3 + nt) * 512), c, 0, 0, 0);
                int e = nt * 16 + l15;
                if (e < 33) {
                    #pragma unroll
                    for (int r = 0; r < 4; ++r) {
                        int gn = node0 + m0 + g4 * 4 + r;
                        if (gn < N_NODES) {
                            float v = c[r];
                            if (dosilu) v = silu_f(v);
                            out[(size_t)gn * F_DIM + h * 33 + e] = v;
                        }
                    }
                }
            }
        }
    };
    auto do_ev = [&](int which, float* __restrict__ out) {
        const unsigned short* Ba = Bl + (size_t)(72 + which * 18) * 512;
        #pragma unroll
        for (int h = 0; h < 3; ++h) {
            bf16x8 a0 = *(const bf16x8*)&arow[256 + h * 64 + g4 * 8];
            bf16x8 a1 = *(const bf16x8*)&arow[256 + h * 64 + 32 + g4 * 8];
            #pragma unroll
            for (int nt = 0; nt < 3; ++nt) {
                f32x4 c = {0.f, 0.f, 0.f, 0.f};
                c = __builtin_amdgcn_mfma_f32_16x16x32_bf16(
                        a0, *(const bf16x8*)(Ba + (size_t)((h * 2 + 0) * 3 + nt) * 512), c, 0, 0, 0);
                c = __builtin_amdgcn_mfma_f32_16x16x32_bf16(
                        a1, *(const bf16x8*)(Ba + (size_t)((h * 2 + 1) * 3 + nt) * 512), c, 0, 0, 0);
                int e = nt * 16 + l15;
                if (e < 44) {
                    #pragma unroll
                    for (int r = 0; r < 4; ++r) {
                        int gn = node0 + m0 + g4 * 4 + r;
                        if (gn < N_NODES)
                            out[(size_t)gn * F_DIM + h * 44 + e] = silu_f(c[r]);
                    }
                }
            }
        }
    };
    if (half == 0) { do_inv(0, q_inv, true); do_inv(1, k_inv, true); }
    else           { do_inv(2, v_inv, false); do_ev(0, q_ev); do_ev(1, k_ev); }
}

// ---------------------------------------------------------------------------
// K_a: edge filters (both layers MFMA) + alpha. q/k gathers hoisted & batched.
// ---------------------------------------------------------------------------
__global__ __launch_bounds__(256) void edge_alpha_kernel(
    const float* __restrict__ ev_feat, const float* __restrict__ rbf,
    const float* __restrict__ cutoffs,
    const int* __restrict__ senders, const int* __restrict__ receivers,
    const int* __restrict__ perm,
    const float* __restrict__ fi_eW1, const float* __restrict__ fe_eW1,
    const unsigned short* __restrict__ B1frag, const float* __restrict__ biasB1,
    const unsigned short* __restrict__ Bfrag, const float* __restrict__ biasC,
    const float* __restrict__ q_inv, const float* __restrict__ k_inv,
    const float* __restrict__ q_ev, const float* __restrict__ k_ev,
    float* __restrict__ galpha, int* __restrict__ gsnd)
{
    __shared__ __align__(16) unsigned short s_hid[2][TE][200];
    __shared__ __align__(16) unsigned short s_ain[TE][40];
    __shared__ float s_d2[TE][16];
    __shared__ float s_ei[3][TE];
    __shared__ float s_c[TE];
    __shared__ int s_snd[TE], s_rcv[TE], s_eid[TE];

    const int e0g = blockIdx.x * TE;
    const int tid = threadIdx.x;

    // ---- P0a: edge meta via CSR perm
    if (tid < TE) {
        int eid = perm[e0g + tid];
        s_eid[tid] = eid;
        int sn = senders[eid], rc = receivers[eid];
        s_snd[tid] = sn; s_rcv[tid] = rc;
        s_c[tid] = cutoffs[eid];
        gsnd[e0g + tid] = sn;
    }
    __syncthreads();
    // ---- P0b: rbf -> bf16 LDS rows; ev_diff^2
    for (int i = tid; i < TE * R_DIM; i += 256) {
        int e = i >> 5, k = i & 31;
        s_ain[e][k] = f2bf(rbf[(size_t)s_eid[e] * R_DIM + k]);
    }
    for (int i = tid; i < TE * EV_DIM; i += 256) {
        int e = i / EV_DIM, j = i - e * EV_DIM;
        float d = ev_feat[(size_t)s_snd[e] * EV_DIM + j]
                - ev_feat[(size_t)s_rcv[e] * EV_DIM + j];
        s_d2[e][j] = d * d;
    }
    __syncthreads();
    if (tid < TE * 3) {
        int e = tid / 3, k2 = tid - e * 3;
        int i0 = (k2 == 0) ? 0 : (k2 == 1) ? 3 : 8;
        int i1 = (k2 == 0) ? 3 : (k2 == 1) ? 8 : 15;
        float s = 0.f;
        for (int i = i0; i < i1; ++i) s += s_d2[e][i];
        s_ei[k2][e] = s;
    }
    __syncthreads();

    const int wv = tid >> 6, l = tid & 63;
    const int f = wv & 1, m0 = (wv >> 1) * 16;
    const int l15 = l & 15, g4 = l >> 4;

    int rcvr[4], sndr[4];
    #pragma unroll
    for (int r = 0; r < 4; ++r) {
        int e = m0 + g4 * 4 + r;
        rcvr[r] = s_rcv[e]; sndr[r] = s_snd[e];
    }

    // ---- q/k gather prefetch: all 72 loads issued up front (overlaps P1+P2)
    const float* qp = f ? q_ev : q_inv;
    const float* kp = f ? k_ev : k_inv;
    float qk[9][4];
    #pragma unroll
    for (int nt = 0; nt < 9; ++nt) {
        const int n = nt * 16 + l15;
        #pragma unroll
        for (int r = 0; r < 4; ++r) {
            float qv = 0.f, kv = 0.f;
            if (n < F_DIM) {
                qv = qp[(size_t)rcvr[r] * F_DIM + n];
                kv = kp[(size_t)sndr[r] * F_DIM + n];
            }
            qk[nt][r] = qv * kv;
        }
    }

    // ---- P1: layer 1 via MFMA (K=32); ev-branch as rank-3 epilogue.
    {
        bf16x8 a1 = *(const bf16x8*)&s_ain[m0 + l15][g4 * 8];
        const unsigned short* B1f = B1frag + (size_t)f * 6144 + (size_t)l * 8;
        const float* eW1f = f ? fe_eW1 : fi_eW1;
        #pragma unroll
        for (int nt = 0; nt < 12; ++nt) {
            f32x4 c = {0.f, 0.f, 0.f, 0.f};
            bf16x8 b1 = *(const bf16x8*)(B1f + (size_t)nt * 512);
            c = __builtin_amdgcn_mfma_f32_16x16x32_bf16(a1, b1, c, 0, 0, 0);
            const int n = nt * 16 + l15;
            const float bias = biasB1[f * 192 + n];
            float w0 = 0.f, w1 = 0.f, w2 = 0.f;
            if (n >= F_DIM && n < 165) {
                w0 = eW1f[n - F_DIM];
                w1 = eW1f[F_Q + n - F_DIM];
                w2 = eW1f[2 * F_Q + n - F_DIM];
            }
            #pragma unroll
            for (int r = 0; r < 4; ++r) {
                int e = m0 + g4 * 4 + r;
                float eic = w0 * s_ei[0][e] + w1 * s_ei[1][e] + w2 * s_ei[2][e];
                float v = silu_f(c[r] + bias + eic);
                s_hid[f][e][n] = f2bf(v);
            }
        }
    }

    // ---- P2: layer-2 MFMA (K=192) + fused alpha epilogue -> galpha
    bf16x8 afr[6];
    {
        const unsigned short* hrow = &s_hid[f][m0 + l15][0];
        #pragma unroll
        for (int kc = 0; kc < 6; ++kc)
            afr[kc] = *(const bf16x8*)&hrow[kc * 32 + g4 * 8];
    }
    const unsigned short* Bf = Bfrag + (size_t)f * 54 * 512 + (size_t)l * 8;

    auto run = [&](auto FC) {
        constexpr int F_ = decltype(FC)::value;
        constexpr int NH = F_ ? 3 : 4;
        constexpr int DD = F_ ? 44 : 33;
        float part[NH][4];
        #pragma unroll
        for (int h = 0; h < NH; ++h)
            #pragma unroll
            for (int r = 0; r < 4; ++r) part[h][r] = 0.f;

        #pragma unroll
        for (int nt = 0; nt < 9; ++nt) {
            f32x4 acc = {0.f, 0.f, 0.f, 0.f};
            #pragma unroll
            for (int kc = 0; kc < 6; ++kc) {
                bf16x8 bfr = *(const bf16x8*)(Bf + (size_t)(kc * 9 + nt) * 512);
                acc = __builtin_amdgcn_mfma_f32_16x16x32_bf16(afr[kc], bfr, acc, 0, 0, 0);
            }
            const int n = nt * 16 + l15;
            const bool nvalid = (n < F_DIM);
            const float bias = biasC[F_ * 144 + n];
            int h0v = (nt * 16) / DD;
            int bsp = (h0v + 1) * DD - nt * 16;
            #pragma unroll
            for (int r = 0; r < 4; ++r) {
                float p = 0.f;
                if (nvalid) p = (acc[r] + bias) * qk[nt][r];
                if (bsp >= 16) {
                    part[h0v][r] += p;
                } else {
                    float plo = (l15 < bsp) ? p : 0.f;
                    part[h0v][r] += plo;
                    if (h0v + 1 < NH) part[h0v + 1][r] += (p - plo);
                }
            }
        }
        #pragma unroll
        for (int h = 0; h < NH; ++h) {
            #pragma unroll
            for (int r = 0; r < 4; ++r) {
                float v = part[h][r];
                v += __shfl_xor(v, 1);
                v += __shfl_xor(v, 2);
                v += __shfl_xor(v, 4);
                v += __shfl_xor(v, 8);
                if (l15 == 0) {
                    int e = m0 + g4 * 4 + r;
                    galpha[(size_t)(e0g + e) * 8 + (F_ ? 4 + h : h)] =
                        v * s_c[e] * (F_ ? RCP_NORM_EV : RCP_NORM_INV);
                }
            }
        }
    };
    if (f == 0) run(std::integral_constant<int, 0>{});
    else        run(std::integral_constant<int, 1>{});
}

// ---------------------------------------------------------------------------
// K_b: node-centric aggregation. 4 nodes/block, 1 wave/node. No atomics.
// ---------------------------------------------------------------------------
__global__ __launch_bounds__(256) void gather_kernel(
    const float* __restrict__ v_inv, const float* __restrict__ sh_vec,
    const float* __restrict__ galpha,
    const int* __restrict__ gsnd, const int* __restrict__ perm,
    const int* __restrict__ off,
    float* __restrict__ a_inv, float* __restrict__ a_ev)
{
    int n = blockIdx.x * 4 + (threadIdx.x >> 6);
    int l = threadIdx.x & 63;
    int beg = off[n], end = off[n + 1];
    int c0 = l, c1 = l + 64, c2 = l + 128;
    int h0 = c0 / 33, h1 = c1 / 33;
    float acc0 = 0.f, acc1 = 0.f, acc2 = 0.f, aev = 0.f;
    int seg = (l < 3) ? 0 : (l < 8) ? 1 : 2;
    for (int p = beg; p < end; ++p) {
        int snd = gsnd[p];
        const float* ga = &galpha[(size_t)p * 8];
        const float* vr = &v_inv[(size_t)snd * F_DIM];
        acc0 += ga[h0] * vr[c0];
        acc1 += ga[h1] * vr[c1];
        if (l < 4) acc2 += ga[3] * vr[c2];
        if (l < EV_DIM) {
            int eid = perm[p];
            aev += ga[4 + seg] * sh_vec[(size_t)eid * EV_DIM + l];
        }
    }
    float* dr = &a_inv[(size_t)n * F_DIM];
    dr[c0] = acc0; dr[c1] = acc1;
    if (l < 4) dr[c2] = acc2;
    if (l < EV_DIM) a_ev[(size_t)n * EV_DIM + l] = aev;
}

// ---------------------------------------------------------------------------
// Kernel 3: epilogue — residuals, 135x135 interaction, outputs. 16 nodes/block.
// ---------------------------------------------------------------------------
__global__ __launch_bounds__(256) void epilogue_kernel(
    const float* __restrict__ inv_feat, const float* __restrict__ ev_feat,
    const float* __restrict__ acc_inv, const float* __restrict__ acc_ev,
    const float* __restrict__ W_int, const float* __restrict__ b_int,
    float* __restrict__ out0, float* __restrict__ out1)
{
    const int NB = 16;
    __shared__ float s_in[NB][INT_DIM + 1];
    __shared__ float s_ev1[NB][EV_DIM + 1];
    __shared__ float s_b[NB][3];
    int n0 = blockIdx.x * NB;
    int tid = threadIdx.x;
    for (int i = tid; i < NB * F_DIM; i += 256) {
        int nb = i / F_DIM, j = i - nb * F_DIM;
        size_t idx = (size_t)(n0 + nb) * F_DIM + j;
        s_in[nb][j] = inv_feat[idx] + acc_inv[idx];
    }
    for (int i = tid; i < NB * EV_DIM; i += 256) {
        int nb = i / EV_DIM, j = i - nb * EV_DIM;
        size_t idx = (size_t)(n0 + nb) * EV_DIM + j;
        s_ev1[nb][j] = ev_feat[idx] + acc_ev[idx];
    }
    __syncthreads();
    if (tid < NB * 3) {
        int nb = tid / 3, k = tid - nb * 3;
        int i0 = (k == 0) ? 0 : (k == 1) ? 3 : 8;
        int i1 = (k == 0) ? 3 : (k == 1) ? 8 : 15;
        float s = 0.f;
        for (int i = i0; i < i1; ++i) { float v = s_ev1[nb][i]; s += v * v; }
        s_in[nb][F_DIM + k] = s;
    }
    __syncthreads();
    if (tid < INT_DIM) {
        int j = tid;
        float b = b_int[j];
        float acc[NB];
        #pragma unroll
        for (int nb = 0; nb < NB; ++nb) acc[nb] = b;
        for (int i = 0; i < INT_DIM; ++i) {
            float w = W_int[i * INT_DIM + j];
            #pragma unroll
            for (int nb = 0; nb < NB; ++nb) acc[nb] += s_in[nb][i] * w;
        }
        if (j < F_DIM) {
            #pragma unroll
            for (int nb = 0; nb < NB; ++nb)
                out0[(size_t)(n0 + nb) * F_DIM + j] = s_in[nb][j] + acc[nb];
        } else {
            #pragma unroll
            for (int nb = 0; nb < NB; ++nb)
                s_b[nb][j - F_DIM] = acc[nb];
        }
    }
    __syncthreads();
    for (int i = tid; i < NB * EV_DIM; i += 256) {
        int nb = i / EV_DIM, ii = i - nb * EV_DIM;
        int seg = (ii < 3) ? 0 : (ii < 8) ? 1 : 2;
        out1[(size_t)(n0 + nb) * EV_DIM + ii] = s_ev1[nb][ii] * (1.f + s_b[nb][seg]);
    }
}

// ---------------------------------------------------------------------------
extern "C" void kernel_launch(void* const* d_in, const int* in_sizes, int n_in,
                              void* d_out, int out_size, void* d_ws, size_t ws_size,
                              hipStream_t stream)
{
    const float* inv_feat  = (const float*)d_in[0];
    const float* ev_feat   = (const float*)d_in[1];
    const float* rbf       = (const float*)d_in[2];
    const float* sh_vec    = (const float*)d_in[3];
    const float* cutoffs   = (const float*)d_in[4];
    const int*   senders   = (const int*)d_in[5];
    const int*   receivers = (const int*)d_in[6];
    const float* Wq_inv = (const float*)d_in[7];
    const float* Wk_inv = (const float*)d_in[8];
    const float* Wv_inv = (const float*)d_in[9];
    const float* Wq_ev  = (const float*)d_in[10];
    const float* Wk_ev  = (const float*)d_in[11];
    const float* fi_rW1 = (const float*)d_in[12];
    const float* fi_rb1 = (const float*)d_in[13];
    const float* fi_rW2 = (const float*)d_in[14];
    const float* fi_rb2 = (const float*)d_in[15];
    const float* fi_eW1 = (const float*)d_in[16];
    const float* fi_eb1 = (const float*)d_in[17];
    const float* fi_eW2 = (const float*)d_in[18];
    const float* fi_eb2 = (const float*)d_in[19];
    const float* fe_rW1 = (const float*)d_in[20];
    const float* fe_rb1 = (const float*)d_in[21];
    const float* fe_rW2 = (const float*)d_in[22];
    const float* fe_rb2 = (const float*)d_in[23];
    const float* fe_eW1 = (const float*)d_in[24];
    const float* fe_eb1 = (const float*)d_in[25];
    const float* fe_eW2 = (const float*)d_in[26];
    const float* fe_eb2 = (const float*)d_in[27];
    const float* W_int  = (const float*)d_in[28];
    const float* b_int  = (const float*)d_in[29];

    const size_t NF = (size_t)N_NODES * F_DIM;
    float* ws    = (float*)d_ws;
    float* q_inv = ws;
    float* k_inv = ws + 1 * NF;
    float* v_inv = ws + 2 * NF;
    float* q_ev  = ws + 3 * NF;
    float* k_ev  = ws + 4 * NF;
    float* galpha = ws + 5 * NF;                       // 400k * 8 floats
    int*   perm   = (int*)(galpha + (size_t)N_EDGES * 8);
    int*   gsnd   = perm + N_EDGES;
    int*   cnt    = gsnd + N_EDGES;
    int*   off    = cnt + N_NODES;
    int*   cursor = off + (N_NODES + 4);
    unsigned short* Bfrag  = (unsigned short*)(cursor + N_NODES);  // 55296
    float*          biasC  = (float*)(Bfrag + 55296);              // 288
    unsigned short* B1frag = (unsigned short*)(biasC + 288);       // 12288
    float*          biasB1 = (float*)(B1frag + 12288);             // 384
    unsigned short* Bnp    = (unsigned short*)(biasB1 + 384);      // 55296
    int* tsum  = (int*)(Bnp + 55296);                              // 64
    int* tbase = tsum + 64;                                        // 64
    float* a_inv = q_inv;              // dead after edge_alpha
    float* a_ev  = k_inv;

    float* out0 = (float*)d_out;
    float* out1 = out0 + NF;

    hipMemsetAsync(cnt, 0, N_NODES * sizeof(int), stream);
    hist_kernel<<<(N_EDGES + 255) / 256, 256, 0, stream>>>(receivers, cnt);
    scan_tile_sum<<<49, 1024, 0, stream>>>(cnt, tsum);
    scan_base<<<1, 64, 0, stream>>>(tsum, tbase);
    scan_tile<<<49, 1024, 0, stream>>>(cnt, tbase, off, cursor);
    scatter_kernel<<<(N_EDGES + 255) / 256, 256, 0, stream>>>(receivers, cursor, perm);

    prep_w2_kernel<<<27, 256, 0, stream>>>(
        fi_rW2, fi_eW2, fe_rW2, fe_eW2,
        fi_rb2, fi_eb2, fe_rb2, fe_eb2, Bfrag, biasC);

    prep_aux_kernel<<<35, 256, 0, stream>>>(
        fi_rW1, fe_rW1, fi_rb1, fi_eb1, fe_rb1, fe_eb1,
        Wq_inv, Wk_inv, Wv_inv, Wq_ev, Wk_ev,
        B1frag, biasB1, Bnp);

    node_proj_kernel<<<(N_NODES + NPB - 1) / NPB, 256, 0, stream>>>(
        inv_feat, Bnp, q_inv, k_inv, v_inv, q_ev, k_ev);

    edge_alpha_kernel<<<N_EDGES / TE, 256, 0, stream>>>(
        ev_feat, rbf, cutoffs, senders, receivers, perm,
        fi_eW1, fe_eW1, B1frag, biasB1, Bfrag, biasC,
        q_inv, k_inv, q_ev, k_ev,
        galpha, gsnd);

    gather_kernel<<<N_NODES / 4, 256, 0, stream>>>(
        v_inv, sh_vec, galpha, gsnd, perm, off, a_inv, a_ev);

    epilogue_kernel<<<N_NODES / 16, 256, 0, stream>>>(
        inv_feat, ev_feat, a_inv, a_ev, W_int, b_int, out0, out1);
}

// Round 7
// 824.899 us; speedup vs baseline: 2.1746x; 1.3707x over previous
//
#include <hip/hip_runtime.h>
#include <type_traits>

#define N_NODES 50000
#define N_EDGES 400000
#define R_DIM   32
#define F_DIM   132
#define EV_DIM  15
#define F_Q     33
#define INT_DIM 135
#define TE      32      // edges per block in K_a
#define NPB     32      // nodes per block in node_proj

#define RCP_NORM_INV 0.17407765595569785f  // 1/sqrt(33)
#define RCP_NORM_EV  0.15075567228888181f  // 1/sqrt(44)

typedef __attribute__((ext_vector_type(8))) short bf16x8;
typedef __attribute__((ext_vector_type(4))) float f32x4;

__device__ __forceinline__ float silu_f(float x) { return x / (1.f + __expf(-x)); }

__device__ __forceinline__ unsigned short f2bf(float x) {
    union { float f; unsigned u; } c; c.f = x;
    unsigned r = c.u + 0x7FFFu + ((c.u >> 16) & 1u);  // RNE
    return (unsigned short)(r >> 16);
}

// ---------------------------------------------------------------------------
// prep_w2: layer-2 weights -> MFMA b-frag order (bf16), K=192 combined.
// ---------------------------------------------------------------------------
__global__ __launch_bounds__(256) void prep_w2_kernel(
    const float* __restrict__ fi_rW2, const float* __restrict__ fi_eW2,
    const float* __restrict__ fe_rW2, const float* __restrict__ fe_eW2,
    const float* __restrict__ fi_rb2, const float* __restrict__ fi_eb2,
    const float* __restrict__ fe_rb2, const float* __restrict__ fe_eb2,
    unsigned short* __restrict__ Bfrag, float* __restrict__ biasC)
{
    int t = blockIdx.x * 256 + threadIdx.x;
    if (t < 6912) {
        int l = t & 63, idx = t >> 6;
        int nt = idx % 9, kc = (idx / 9) % 6, f = idx / 54;
        const float* rW2 = f ? fe_rW2 : fi_rW2;
        const float* eW2 = f ? fe_eW2 : fi_eW2;
        int n = nt * 16 + (l & 15);
        unsigned short v[8];
        #pragma unroll
        for (int j = 0; j < 8; ++j) {
            int k = kc * 32 + (l >> 4) * 8 + j;
            float w = 0.f;
            if (n < F_DIM) {
                if (k < F_DIM) w = rW2[k * F_DIM + n];
                else if (k < F_DIM + F_Q) w = eW2[(k - F_DIM) * F_DIM + n];
            }
            v[j] = f2bf(w);
        }
        *(uint4*)&Bfrag[(size_t)t * 8] = *(const uint4*)v;
    }
    if (blockIdx.x == 0) {
        for (int i = threadIdx.x; i < 288; i += 256) {
            int f = i / 144, n = i % 144;
            const float* rb2 = f ? fe_rb2 : fi_rb2;
            const float* eb2 = f ? fe_eb2 : fi_eb2;
            biasC[i] = (n < F_DIM) ? (rb2[n] + eb2[n]) : 0.f;
        }
    }
}

// ---------------------------------------------------------------------------
// prep_aux: edge layer-1 b-frags + biasB1 + node-proj b-frags (Bnp).
// Bnp blocks: Qi 0-23, Ki 24-47, Vi 48-71 (4h x 2kc x 3nt), Qe 72-89, Ke 90-107.
// ---------------------------------------------------------------------------
__global__ __launch_bounds__(256) void prep_aux_kernel(
    const float* __restrict__ fi_rW1, const float* __restrict__ fe_rW1,
    const float* __restrict__ fi_rb1, const float* __restrict__ fi_eb1,
    const float* __restrict__ fe_rb1, const float* __restrict__ fe_eb1,
    const float* __restrict__ Wq_inv, const float* __restrict__ Wk_inv,
    const float* __restrict__ Wv_inv,
    const float* __restrict__ Wq_ev, const float* __restrict__ Wk_ev,
    unsigned short* __restrict__ B1frag, float* __restrict__ biasB1,
    unsigned short* __restrict__ Bnp)
{
    int t = blockIdx.x * 256 + threadIdx.x;
    if (t < 1536) {
        int l = t & 63, idx = t >> 6;     // idx = f*12 + nt
        int nt = idx % 12, f = idx / 12;
        const float* rW1 = f ? fe_rW1 : fi_rW1;
        int n = nt * 16 + (l & 15);
        unsigned short v[8];
        #pragma unroll
        for (int j = 0; j < 8; ++j) {
            int k = (l >> 4) * 8 + j;
            float w = (n < F_DIM) ? rW1[k * F_DIM + n] : 0.f;
            v[j] = f2bf(w);
        }
        *(uint4*)&B1frag[(size_t)t * 8] = *(const uint4*)v;
    } else if (t < 1920) {
        int i = t - 1536;
        int f = i / 192, n = i % 192;
        const float* rb1 = f ? fe_rb1 : fi_rb1;
        const float* eb1 = f ? fe_eb1 : fi_eb1;
        biasB1[i] = (n < F_DIM) ? rb1[n] : ((n < 165) ? eb1[n - F_DIM] : 0.f);
    } else if (t < 1920 + 6912) {
        int u = t - 1920;
        int l = u & 63, blk = u >> 6;
        int n = 0; const float* W = nullptr; int D = 0, h = 0, kc = 0;
        if (blk < 72) {
            int arr = blk / 24, wb = blk % 24;
            h = wb / 6; kc = (wb % 6) / 3; int nt = wb % 3;
            W = (arr == 0) ? Wq_inv : (arr == 1) ? Wk_inv : Wv_inv;
            D = 33; n = nt * 16 + (l & 15);
            W += h * 1089;
        } else {
            int b2 = blk - 72;
            int which = b2 / 18, wb = b2 % 18;
            h = wb / 6; kc = (wb % 6) / 3; int nt = wb % 3;
            W = which ? Wk_ev : Wq_ev;
            D = 44; n = nt * 16 + (l & 15);
            W += h * 1936;
        }
        unsigned short v[8];
        #pragma unroll
        for (int j = 0; j < 8; ++j) {
            int k = kc * 32 + (l >> 4) * 8 + j;
            float w = (k < D && n < D) ? W[k * D + n] : 0.f;
            v[j] = f2bf(w);
        }
        *(uint4*)&Bnp[(size_t)u * 8] = *(const uint4*)v;
    }
}

// ---------------------------------------------------------------------------
// CSR build: histogram -> coalesced 3-phase scan -> scatter permutation
// ---------------------------------------------------------------------------
__global__ __launch_bounds__(256) void hist_kernel(
    const int* __restrict__ receivers, int* __restrict__ cnt)
{
    int i = blockIdx.x * 256 + threadIdx.x;
    if (i < N_EDGES) atomicAdd(&cnt[receivers[i]], 1);
}

__global__ __launch_bounds__(1024) void scan_tile_sum(
    const int* __restrict__ cnt, int* __restrict__ tsum)
{
    int idx = blockIdx.x * 1024 + threadIdx.x;
    int v = (idx < N_NODES) ? cnt[idx] : 0;
    for (int o = 32; o > 0; o >>= 1) v += __shfl_down(v, o);
    __shared__ int wsum[16];
    if ((threadIdx.x & 63) == 0) wsum[threadIdx.x >> 6] = v;
    __syncthreads();
    if (threadIdx.x == 0) {
        int s = 0;
        for (int i = 0; i < 16; ++i) s += wsum[i];
        tsum[blockIdx.x] = s;
    }
}

__global__ __launch_bounds__(64) void scan_base(
    const int* __restrict__ tsum, int* __restrict__ tbase)
{
    if (threadIdx.x == 0) {
        int run = 0;
        for (int i = 0; i < 49; ++i) { tbase[i] = run; run += tsum[i]; }
    }
}

__global__ __launch_bounds__(1024) void scan_tile(
    const int* __restrict__ cnt, const int* __restrict__ tbase,
    int* __restrict__ off, int* __restrict__ cursor)
{
    __shared__ int s[1024];
    int t = threadIdx.x;
    int idx = blockIdx.x * 1024 + t;
    int v = (idx < N_NODES) ? cnt[idx] : 0;
    s[t] = v;
    __syncthreads();
    for (int d = 1; d < 1024; d <<= 1) {
        int x = (t >= d) ? s[t - d] : 0;
        __syncthreads();
        s[t] += x;
        __syncthreads();
    }
    int o = tbase[blockIdx.x] + s[t] - v;
    if (idx < N_NODES) { off[idx] = o; cursor[idx] = o; }
    if (idx == 0) off[N_NODES] = N_EDGES;
}

__global__ __launch_bounds__(256) void scatter_kernel(
    const int* __restrict__ receivers, int* __restrict__ cursor,
    int* __restrict__ perm)
{
    int i = blockIdx.x * 256 + threadIdx.x;
    if (i < N_EDGES) {
        int pos = atomicAdd(&cursor[receivers[i]], 1);
        perm[pos] = i;
    }
}

// ---------------------------------------------------------------------------
// Kernel 1: node projections via MFMA. 32 nodes/block, 4 waves.
// ---------------------------------------------------------------------------
__global__ __launch_bounds__(256) void node_proj_kernel(
    const float* __restrict__ x,
    const unsigned short* __restrict__ Bnp,
    float* __restrict__ q_inv, float* __restrict__ k_inv, float* __restrict__ v_inv,
    float* __restrict__ q_ev, float* __restrict__ k_ev)
{
    __shared__ __align__(16) unsigned short sx[NPB][456];
    const int node0 = blockIdx.x * NPB;
    const int tid = threadIdx.x;
    for (int i = tid; i < NPB * 448; i += 256) {
        int nd = i / 448, t = i % 448;
        int seg = t >> 6, d = t & 63;
        float v = 0.f;
        int gn = node0 + nd;
        if (gn < N_NODES) {
            if (seg < 4) { if (d < 33) v = x[(size_t)gn * F_DIM + seg * 33 + d]; }
            else         { int h = seg - 4; if (d < 44) v = x[(size_t)gn * F_DIM + h * 44 + d]; }
        }
        sx[nd][t] = f2bf(v);
    }
    __syncthreads();
    const int wv = tid >> 6, l = tid & 63, l15 = l & 15, g4 = l >> 4;
    const int half = wv & 1, m0 = (wv >> 1) * 16;
    const unsigned short* arow = &sx[m0 + l15][0];
    const unsigned short* Bl = Bnp + (size_t)l * 8;

    auto do_inv = [&](int arr, float* __restrict__ out, bool dosilu) {
        const unsigned short* Ba = Bl + (size_t)arr * 24 * 512;
        #pragma unroll
        for (int h = 0; h < 4; ++h) {
            bf16x8 a0 = *(const bf16x8*)&arow[h * 64 + g4 * 8];
            bf16x8 a1 = *(const bf16x8*)&arow[h * 64 + 32 + g4 * 8];
            #pragma unroll
            for (int nt = 0; nt < 3; ++nt) {
                f32x4 c = {0.f, 0.f, 0.f, 0.f};
                c = __builtin_amdgcn_mfma_f32_16x16x32_bf16(
                        a0, *(const bf16x8*)(Ba + (size_t)((h * 2 + 0) * 3 + nt) * 512), c, 0, 0, 0);
                c = __builtin_amdgcn_mfma_f32_16x16x32_bf16(
                        a1, *(const bf16x8*)(Ba + (size_t)((h * 2 + 1) * 3 + nt) * 512), c, 0, 0, 0);
                int e = nt * 16 + l15;
                if (e < 33) {
                    #pragma unroll
                    for (int r = 0; r < 4; ++r) {
                        int gn = node0 + m0 + g4 * 4 + r;
                        if (gn < N_NODES) {
                            float v = c[r];
                            if (dosilu) v = silu_f(v);
                            out[(size_t)gn * F_DIM + h * 33 + e] = v;
                        }
                    }
                }
            }
        }
    };
    auto do_ev = [&](int which, float* __restrict__ out) {
        const unsigned short* Ba = Bl + (size_t)(72 + which * 18) * 512;
        #pragma unroll
        for (int h = 0; h < 3; ++h) {
            bf16x8 a0 = *(const bf16x8*)&arow[256 + h * 64 + g4 * 8];
            bf16x8 a1 = *(const bf16x8*)&arow[256 + h * 64 + 32 + g4 * 8];
            #pragma unroll
            for (int nt = 0; nt < 3; ++nt) {
                f32x4 c = {0.f, 0.f, 0.f, 0.f};
                c = __builtin_amdgcn_mfma_f32_16x16x32_bf16(
                        a0, *(const bf16x8*)(Ba + (size_t)((h * 2 + 0) * 3 + nt) * 512), c, 0, 0, 0);
                c = __builtin_amdgcn_mfma_f32_16x16x32_bf16(
                        a1, *(const bf16x8*)(Ba + (size_t)((h * 2 + 1) * 3 + nt) * 512), c, 0, 0, 0);
                int e = nt * 16 + l15;
                if (e < 44) {
                    #pragma unroll
                    for (int r = 0; r < 4; ++r) {
                        int gn = node0 + m0 + g4 * 4 + r;
                        if (gn < N_NODES)
                            out[(size_t)gn * F_DIM + h * 44 + e] = silu_f(c[r]);
                    }
                }
            }
        }
    };
    if (half == 0) { do_inv(0, q_inv, true); do_inv(1, k_inv, true); }
    else           { do_inv(2, v_inv, false); do_ev(0, q_ev); do_ev(1, k_ev); }
}

// ---------------------------------------------------------------------------
// K_a: edge filters (both layers MFMA) + alpha. q/k gathers software-pipelined
// at depth 2 inside P2 (raw values buffered; consumed only in the epilogue).
// ---------------------------------------------------------------------------
__global__ __launch_bounds__(256) void edge_alpha_kernel(
    const float* __restrict__ ev_feat, const float* __restrict__ rbf,
    const float* __restrict__ cutoffs,
    const int* __restrict__ senders, const int* __restrict__ receivers,
    const int* __restrict__ perm,
    const float* __restrict__ fi_eW1, const float* __restrict__ fe_eW1,
    const unsigned short* __restrict__ B1frag, const float* __restrict__ biasB1,
    const unsigned short* __restrict__ Bfrag, const float* __restrict__ biasC,
    const float* __restrict__ q_inv, const float* __restrict__ k_inv,
    const float* __restrict__ q_ev, const float* __restrict__ k_ev,
    float* __restrict__ galpha, int* __restrict__ gsnd)
{
    __shared__ __align__(16) unsigned short s_hid[2][TE][200];
    __shared__ __align__(16) unsigned short s_ain[TE][40];
    __shared__ float s_d2[TE][16];
    __shared__ float s_ei[3][TE];
    __shared__ float s_c[TE];
    __shared__ int s_snd[TE], s_rcv[TE], s_eid[TE];

    const int e0g = blockIdx.x * TE;
    const int tid = threadIdx.x;

    // ---- P0a: edge meta via CSR perm
    if (tid < TE) {
        int eid = perm[e0g + tid];
        s_eid[tid] = eid;
        int sn = senders[eid], rc = receivers[eid];
        s_snd[tid] = sn; s_rcv[tid] = rc;
        s_c[tid] = cutoffs[eid];
        gsnd[e0g + tid] = sn;
    }
    __syncthreads();
    // ---- P0b: rbf -> bf16 LDS rows; ev_diff^2
    for (int i = tid; i < TE * R_DIM; i += 256) {
        int e = i >> 5, k = i & 31;
        s_ain[e][k] = f2bf(rbf[(size_t)s_eid[e] * R_DIM + k]);
    }
    for (int i = tid; i < TE * EV_DIM; i += 256) {
        int e = i / EV_DIM, j = i - e * EV_DIM;
        float d = ev_feat[(size_t)s_snd[e] * EV_DIM + j]
                - ev_feat[(size_t)s_rcv[e] * EV_DIM + j];
        s_d2[e][j] = d * d;
    }
    __syncthreads();
    if (tid < TE * 3) {
        int e = tid / 3, k2 = tid - e * 3;
        int i0 = (k2 == 0) ? 0 : (k2 == 1) ? 3 : 8;
        int i1 = (k2 == 0) ? 3 : (k2 == 1) ? 8 : 15;
        float s = 0.f;
        for (int i = i0; i < i1; ++i) s += s_d2[e][i];
        s_ei[k2][e] = s;
    }
    __syncthreads();

    const int wv = tid >> 6, l = tid & 63;
    const int f = wv & 1, m0 = (wv >> 1) * 16;
    const int l15 = l & 15, g4 = l >> 4;

    int rcvr[4], sndr[4];
    #pragma unroll
    for (int r = 0; r < 4; ++r) {
        int e = m0 + g4 * 4 + r;
        rcvr[r] = s_rcv[e]; sndr[r] = s_snd[e];
    }

    // ---- P1: layer 1 via MFMA (K=32); ev-branch as rank-3 epilogue.
    {
        bf16x8 a1 = *(const bf16x8*)&s_ain[m0 + l15][g4 * 8];
        const unsigned short* B1f = B1frag + (size_t)f * 6144 + (size_t)l * 8;
        const float* eW1f = f ? fe_eW1 : fi_eW1;
        #pragma unroll
        for (int nt = 0; nt < 12; ++nt) {
            f32x4 c = {0.f, 0.f, 0.f, 0.f};
            bf16x8 b1 = *(const bf16x8*)(B1f + (size_t)nt * 512);
            c = __builtin_amdgcn_mfma_f32_16x16x32_bf16(a1, b1, c, 0, 0, 0);
            const int n = nt * 16 + l15;
            const float bias = biasB1[f * 192 + n];
            float w0 = 0.f, w1 = 0.f, w2 = 0.f;
            if (n >= F_DIM && n < 165) {
                w0 = eW1f[n - F_DIM];
                w1 = eW1f[F_Q + n - F_DIM];
                w2 = eW1f[2 * F_Q + n - F_DIM];
            }
            #pragma unroll
            for (int r = 0; r < 4; ++r) {
                int e = m0 + g4 * 4 + r;
                float eic = w0 * s_ei[0][e] + w1 * s_ei[1][e] + w2 * s_ei[2][e];
                float v = silu_f(c[r] + bias + eic);
                s_hid[f][e][n] = f2bf(v);
            }
        }
    }

    // ---- P2: layer-2 MFMA (K=192) + pipelined q/k gathers + alpha epilogue
    bf16x8 afr[6];
    {
        const unsigned short* hrow = &s_hid[f][m0 + l15][0];
        #pragma unroll
        for (int kc = 0; kc < 6; ++kc)
            afr[kc] = *(const bf16x8*)&hrow[kc * 32 + g4 * 8];
    }
    const unsigned short* Bf = Bfrag + (size_t)f * 54 * 512 + (size_t)l * 8;

    auto run = [&](auto FC) {
        constexpr int F_ = decltype(FC)::value;
        constexpr int NH = F_ ? 3 : 4;
        constexpr int DD = F_ ? 44 : 33;
        const float* qp = F_ ? q_ev : q_inv;
        const float* kp = F_ ? k_ev : k_inv;
        float part[NH][4];
        #pragma unroll
        for (int h = 0; h < NH; ++h)
            #pragma unroll
            for (int r = 0; r < 4; ++r) part[h][r] = 0.f;

        auto ldtile = [&](int nt, float (&bq)[4], float (&bk)[4]) {
            const int n = nt * 16 + l15;
            #pragma unroll
            for (int r = 0; r < 4; ++r) {
                float qv = 0.f, kv = 0.f;
                if (n < F_DIM) {
                    qv = qp[(size_t)rcvr[r] * F_DIM + n];
                    kv = kp[(size_t)sndr[r] * F_DIM + n];
                }
                bq[r] = qv; bk[r] = kv;
            }
        };

        float bq[2][4], bk[2][4];
        ldtile(0, bq[0], bk[0]);
        ldtile(1, bq[1], bk[1]);

        #pragma unroll
        for (int nt = 0; nt < 9; ++nt) {
            // consume-copy current tile's buffered q/k, then refill for nt+2
            float cq[4], ck[4];
            #pragma unroll
            for (int r = 0; r < 4; ++r) { cq[r] = bq[nt & 1][r]; ck[r] = bk[nt & 1][r]; }
            if (nt + 2 < 9) ldtile(nt + 2, bq[nt & 1], bk[nt & 1]);

            f32x4 acc = {0.f, 0.f, 0.f, 0.f};
            #pragma unroll
            for (int kc = 0; kc < 6; ++kc) {
                bf16x8 bfr = *(const bf16x8*)(Bf + (size_t)(kc * 9 + nt) * 512);
                acc = __builtin_amdgcn_mfma_f32_16x16x32_bf16(afr[kc], bfr, acc, 0, 0, 0);
            }
            const int n = nt * 16 + l15;
            const bool nvalid = (n < F_DIM);
            const float bias = biasC[F_ * 144 + n];
            int h0v = (nt * 16) / DD;
            int bsp = (h0v + 1) * DD - nt * 16;
            #pragma unroll
            for (int r = 0; r < 4; ++r) {
                float p = 0.f;
                if (nvalid) p = (acc[r] + bias) * cq[r] * ck[r];
                if (bsp >= 16) {
                    part[h0v][r] += p;
                } else {
                    float plo = (l15 < bsp) ? p : 0.f;
                    part[h0v][r] += plo;
                    if (h0v + 1 < NH) part[h0v + 1][r] += (p - plo);
                }
            }
        }
        #pragma unroll
        for (int h = 0; h < NH; ++h) {
            #pragma unroll
            for (int r = 0; r < 4; ++r) {
                float v = part[h][r];
                v += __shfl_xor(v, 1);
                v += __shfl_xor(v, 2);
                v += __shfl_xor(v, 4);
                v += __shfl_xor(v, 8);
                if (l15 == 0) {
                    int e = m0 + g4 * 4 + r;
                    galpha[(size_t)(e0g + e) * 8 + (F_ ? 4 + h : h)] =
                        v * s_c[e] * (F_ ? RCP_NORM_EV : RCP_NORM_INV);
                }
            }
        }
    };
    if (f == 0) run(std::integral_constant<int, 0>{});
    else        run(std::integral_constant<int, 1>{});
}

// ---------------------------------------------------------------------------
// K_b: node-centric aggregation. 4 nodes/block, 1 wave/node. No atomics.
// ---------------------------------------------------------------------------
__global__ __launch_bounds__(256) void gather_kernel(
    const float* __restrict__ v_inv, const float* __restrict__ sh_vec,
    const float* __restrict__ galpha,
    const int* __restrict__ gsnd, const int* __restrict__ perm,
    const int* __restrict__ off,
    float* __restrict__ a_inv, float* __restrict__ a_ev)
{
    int n = blockIdx.x * 4 + (threadIdx.x >> 6);
    int l = threadIdx.x & 63;
    int beg = off[n], end = off[n + 1];
    int c0 = l, c1 = l + 64, c2 = l + 128;
    int h0 = c0 / 33, h1 = c1 / 33;
    float acc0 = 0.f, acc1 = 0.f, acc2 = 0.f, aev = 0.f;
    int seg = (l < 3) ? 0 : (l < 8) ? 1 : 2;
    #pragma unroll 2
    for (int p = beg; p < end; ++p) {
        int snd = gsnd[p];
        const float* ga = &galpha[(size_t)p * 8];
        const float* vr = &v_inv[(size_t)snd * F_DIM];
        acc0 += ga[h0] * vr[c0];
        acc1 += ga[h1] * vr[c1];
        if (l < 4) acc2 += ga[3] * vr[c2];
        if (l < EV_DIM) {
            int eid = perm[p];
            aev += ga[4 + seg] * sh_vec[(size_t)eid * EV_DIM + l];
        }
    }
    float* dr = &a_inv[(size_t)n * F_DIM];
    dr[c0] = acc0; dr[c1] = acc1;
    if (l < 4) dr[c2] = acc2;
    if (l < EV_DIM) a_ev[(size_t)n * EV_DIM + l] = aev;
}

// ---------------------------------------------------------------------------
// Kernel 3: epilogue — residuals, 135x135 interaction, outputs. 16 nodes/block.
// ---------------------------------------------------------------------------
__global__ __launch_bounds__(256) void epilogue_kernel(
    const float* __restrict__ inv_feat, const float* __restrict__ ev_feat,
    const float* __restrict__ acc_inv, const float* __restrict__ acc_ev,
    const float* __restrict__ W_int, const float* __restrict__ b_int,
    float* __restrict__ out0, float* __restrict__ out1)
{
    const int NB = 16;
    __shared__ float s_in[NB][INT_DIM + 1];
    __shared__ float s_ev1[NB][EV_DIM + 1];
    __shared__ float s_b[NB][3];
    int n0 = blockIdx.x * NB;
    int tid = threadIdx.x;
    for (int i = tid; i < NB * F_DIM; i += 256) {
        int nb = i / F_DIM, j = i - nb * F_DIM;
        size_t idx = (size_t)(n0 + nb) * F_DIM + j;
        s_in[nb][j] = inv_feat[idx] + acc_inv[idx];
    }
    for (int i = tid; i < NB * EV_DIM; i += 256) {
        int nb = i / EV_DIM, j = i - nb * EV_DIM;
        size_t idx = (size_t)(n0 + nb) * EV_DIM + j;
        s_ev1[nb][j] = ev_feat[idx] + acc_ev[idx];
    }
    __syncthreads();
    if (tid < NB * 3) {
        int nb = tid / 3, k = tid - nb * 3;
        int i0 = (k == 0) ? 0 : (k == 1) ? 3 : 8;
        int i1 = (k == 0) ? 3 : (k == 1) ? 8 : 15;
        float s = 0.f;
        for (int i = i0; i < i1; ++i) { float v = s_ev1[nb][i]; s += v * v; }
        s_in[nb][F_DIM + k] = s;
    }
    __syncthreads();
    if (tid < INT_DIM) {
        int j = tid;
        float b = b_int[j];
        float acc[NB];
        #pragma unroll
        for (int nb = 0; nb < NB; ++nb) acc[nb] = b;
        for (int i = 0; i < INT_DIM; ++i) {
            float w = W_int[i * INT_DIM + j];
            #pragma unroll
            for (int nb = 0; nb < NB; ++nb) acc[nb] += s_in[nb][i] * w;
        }
        if (j < F_DIM) {
            #pragma unroll
            for (int nb = 0; nb < NB; ++nb)
                out0[(size_t)(n0 + nb) * F_DIM + j] = s_in[nb][j] + acc[nb];
        } else {
            #pragma unroll
            for (int nb = 0; nb < NB; ++nb)
                s_b[nb][j - F_DIM] = acc[nb];
        }
    }
    __syncthreads();
    for (int i = tid; i < NB * EV_DIM; i += 256) {
        int nb = i / EV_DIM, ii = i - nb * EV_DIM;
        int seg = (ii < 3) ? 0 : (ii < 8) ? 1 : 2;
        out1[(size_t)(n0 + nb) * EV_DIM + ii] = s_ev1[nb][ii] * (1.f + s_b[nb][seg]);
    }
}

// ---------------------------------------------------------------------------
extern "C" void kernel_launch(void* const* d_in, const int* in_sizes, int n_in,
                              void* d_out, int out_size, void* d_ws, size_t ws_size,
                              hipStream_t stream)
{
    const float* inv_feat  = (const float*)d_in[0];
    const float* ev_feat   = (const float*)d_in[1];
    const float* rbf       = (const float*)d_in[2];
    const float* sh_vec    = (const float*)d_in[3];
    const float* cutoffs   = (const float*)d_in[4];
    const int*   senders   = (const int*)d_in[5];
    const int*   receivers = (const int*)d_in[6];
    const float* Wq_inv = (const float*)d_in[7];
    const float* Wk_inv = (const float*)d_in[8];
    const float* Wv_inv = (const float*)d_in[9];
    const float* Wq_ev  = (const float*)d_in[10];
    const float* Wk_ev  = (const float*)d_in[11];
    const float* fi_rW1 = (const float*)d_in[12];
    const float* fi_rb1 = (const float*)d_in[13];
    const float* fi_rW2 = (const float*)d_in[14];
    const float* fi_rb2 = (const float*)d_in[15];
    const float* fi_eW1 = (const float*)d_in[16];
    const float* fi_eb1 = (const float*)d_in[17];
    const float* fi_eW2 = (const float*)d_in[18];
    const float* fi_eb2 = (const float*)d_in[19];
    const float* fe_rW1 = (const float*)d_in[20];
    const float* fe_rb1 = (const float*)d_in[21];
    const float* fe_rW2 = (const float*)d_in[22];
    const float* fe_rb2 = (const float*)d_in[23];
    const float* fe_eW1 = (const float*)d_in[24];
    const float* fe_eb1 = (const float*)d_in[25];
    const float* fe_eW2 = (const float*)d_in[26];
    const float* fe_eb2 = (const float*)d_in[27];
    const float* W_int  = (const float*)d_in[28];
    const float* b_int  = (const float*)d_in[29];

    const size_t NF = (size_t)N_NODES * F_DIM;
    float* ws    = (float*)d_ws;
    float* q_inv = ws;
    float* k_inv = ws + 1 * NF;
    float* v_inv = ws + 2 * NF;
    float* q_ev  = ws + 3 * NF;
    float* k_ev  = ws + 4 * NF;
    float* galpha = ws + 5 * NF;
    int*   perm   = (int*)(galpha + (size_t)N_EDGES * 8);
    int*   gsnd   = perm + N_EDGES;
    int*   cnt    = gsnd + N_EDGES;
    int*   off    = cnt + N_NODES;
    int*   cursor = off + (N_NODES + 4);
    unsigned short* Bfrag  = (unsigned short*)(cursor + N_NODES);
    float*          biasC  = (float*)(Bfrag + 55296);
    unsigned short* B1frag = (unsigned short*)(biasC + 288);
    float*          biasB1 = (float*)(B1frag + 12288);
    unsigned short* Bnp    = (unsigned short*)(biasB1 + 384);
    int* tsum  = (int*)(Bnp + 55296);
    int* tbase = tsum + 64;
    float* a_inv = q_inv;
    float* a_ev  = k_inv;

    float* out0 = (float*)d_out;
    float* out1 = out0 + NF;

    hipMemsetAsync(cnt, 0, N_NODES * sizeof(int), stream);
    hist_kernel<<<(N_EDGES + 255) / 256, 256, 0, stream>>>(receivers, cnt);
    scan_tile_sum<<<49, 1024, 0, stream>>>(cnt, tsum);
    scan_base<<<1, 64, 0, stream>>>(tsum, tbase);
    scan_tile<<<49, 1024, 0, stream>>>(cnt, tbase, off, cursor);
    scatter_kernel<<<(N_EDGES + 255) / 256, 256, 0, stream>>>(receivers, cursor, perm);

    prep_w2_kernel<<<27, 256, 0, stream>>>(
        fi_rW2, fi_eW2, fe_rW2, fe_eW2,
        fi_rb2, fi_eb2, fe_rb2, fe_eb2, Bfrag, biasC);

    prep_aux_kernel<<<35, 256, 0, stream>>>(
        fi_rW1, fe_rW1, fi_rb1, fi_eb1, fe_rb1, fe_eb1,
        Wq_inv, Wk_inv, Wv_inv, Wq_ev, Wk_ev,
        B1frag, biasB1, Bnp);

    node_proj_kernel<<<(N_NODES + NPB - 1) / NPB, 256, 0, stream>>>(
        inv_feat, Bnp, q_inv, k_inv, v_inv, q_ev, k_ev);

    edge_alpha_kernel<<<N_EDGES / TE, 256, 0, stream>>>(
        ev_feat, rbf, cutoffs, senders, receivers, perm,
        fi_eW1, fe_eW1, B1frag, biasB1, Bfrag, biasC,
        q_inv, k_inv, q_ev, k_ev,
        galpha, gsnd);

    gather_kernel<<<N_NODES / 4, 256, 0, stream>>>(
        v_inv, sh_vec, galpha, gsnd, perm, off, a_inv, a_ev);

    epilogue_kernel<<<N_NODES / 16, 256, 0, stream>>>(
        inv_feat, ev_feat, a_inv, a_ev, W_int, b_int, out0, out1);
}